// Round 1
// baseline (6112.655 us; speedup 1.0000x reference)
//
#include <hip/hip_runtime.h>
#include <math.h>

// ---------------------------------------------------------------------------
// CrossModal_NN — round 1: correct fp32 baseline.
// Dominant cost: bilinear einsum == GEMM [3072,65536]x[256,65536]^T with
// on-the-fly A (A[m, i*256+j] = c_va[m,i]*c_av[m,j]). fp32 vector baseline;
// MFMA conversion planned for round 2 once correctness is anchored.
// Workspace use: ~54.7 MB fp32.
// ---------------------------------------------------------------------------

constexpr float NORM = 0.0625f; // 1/sqrt(256), applied AFTER softmax (faithful)

// ---------------- generic fp32 GEMM: C = act(A @ W^T + bias) ---------------
// A [M,K] row-major, W [N,K] row-major, C [M,N]. Tile 64x64, BK=32, 256 thr.
template<int ACT>
__global__ __launch_bounds__(256)
void gemm_bt(const float* __restrict__ A, const float* __restrict__ W,
             const float* __restrict__ bias, float* __restrict__ C,
             int M, int N, int K)
{
    __shared__ __align__(16) float sA[32][68];
    __shared__ __align__(16) float sB[32][68];
    const int tid = threadIdx.x;
    const int m0 = blockIdx.y * 64;
    const int n0 = blockIdx.x * 64;
    const int tx = tid & 15;   // n micro
    const int ty = tid >> 4;   // m micro
    const int kk = tid & 31;   // load: k within tile
    const int rr = tid >> 5;   // load: row group
    float acc[4][4] = {};
    for (int k0 = 0; k0 < K; k0 += 32) {
        #pragma unroll
        for (int p = 0; p < 8; p++) {
            int mm = rr + p * 8;
            int m  = m0 + mm;
            int k  = k0 + kk;
            sA[kk][mm] = (m < M && k < K) ? A[(size_t)m * K + k] : 0.f;
        }
        #pragma unroll
        for (int p = 0; p < 8; p++) {
            int nn = rr + p * 8;
            int n  = n0 + nn;
            int k  = k0 + kk;
            sB[kk][nn] = (n < N && k < K) ? W[(size_t)n * K + k] : 0.f;
        }
        __syncthreads();
        #pragma unroll
        for (int q = 0; q < 32; q++) {
            float av[4], bv[4];
            #pragma unroll
            for (int i = 0; i < 4; i++) av[i] = sA[q][ty * 4 + i];
            #pragma unroll
            for (int j = 0; j < 4; j++) bv[j] = sB[q][tx * 4 + j];
            #pragma unroll
            for (int i = 0; i < 4; i++)
                #pragma unroll
                for (int j = 0; j < 4; j++)
                    acc[i][j] += av[i] * bv[j];
        }
        __syncthreads();
    }
    #pragma unroll
    for (int i = 0; i < 4; i++) {
        int m = m0 + ty * 4 + i;
        if (m >= M) continue;
        #pragma unroll
        for (int j = 0; j < 4; j++) {
            int n = n0 + tx * 4 + j;
            if (n >= N) continue;
            float v = acc[i][j];
            if (bias) v += bias[n];
            if (ACT) v = fmaxf(v, 0.f);
            C[(size_t)m * N + n] = v;
        }
    }
}

// ---------------- bilinear: out[m,o] += sum_k cva[m,k>>8]*cav[m,k&255]*Wb[o,k]
// M=3072, N=256, K=65536. Split-K over gridDim.z (8 chunks of 8192), atomicAdd.
__global__ __launch_bounds__(256)
void bilinear_bt(const float* __restrict__ cva, const float* __restrict__ cav,
                 const float* __restrict__ Wb, float* __restrict__ out)
{
    __shared__ __align__(16) float sA[32][68];
    __shared__ __align__(16) float sB[32][68];
    const int tid = threadIdx.x;
    const int m0 = blockIdx.y * 64;
    const int n0 = blockIdx.x * 64;
    const int tx = tid & 15;
    const int ty = tid >> 4;
    const int kk = tid & 31;
    const int rr = tid >> 5;
    float acc[4][4] = {};
    const int kbeg = blockIdx.z * 8192;
    const int kend = kbeg + 8192;
    for (int k0 = kbeg; k0 < kend; k0 += 32) {
        const int i0 = k0 >> 8;     // constant within BK=32 tile (32 | 256)
        const int j0 = k0 & 255;
        #pragma unroll
        for (int p = 0; p < 8; p++) {
            int mm = rr + p * 8;
            int m  = m0 + mm;
            sA[kk][mm] = cva[(size_t)m * 256 + i0] * cav[(size_t)m * 256 + j0 + kk];
        }
        #pragma unroll
        for (int p = 0; p < 8; p++) {
            int nn = rr + p * 8;
            sB[kk][nn] = Wb[(size_t)(n0 + nn) * 65536 + k0 + kk];
        }
        __syncthreads();
        #pragma unroll
        for (int q = 0; q < 32; q++) {
            float av[4], bv[4];
            #pragma unroll
            for (int i = 0; i < 4; i++) av[i] = sA[q][ty * 4 + i];
            #pragma unroll
            for (int j = 0; j < 4; j++) bv[j] = sB[q][tx * 4 + j];
            #pragma unroll
            for (int i = 0; i < 4; i++)
                #pragma unroll
                for (int j = 0; j < 4; j++)
                    acc[i][j] += av[i] * bv[j];
        }
        __syncthreads();
    }
    #pragma unroll
    for (int i = 0; i < 4; i++) {
        int m = m0 + ty * 4 + i;
        #pragma unroll
        for (int j = 0; j < 4; j++) {
            int n = n0 + tx * 4 + j;
            atomicAdd(&out[(size_t)m * 256 + n], acc[i][j]);
        }
    }
}

// ---------------- attention: 4 maps, S=3, softmax then *NORM, alpha = att@x --
__global__ __launch_bounds__(256)
void attn_kernel(const float* __restrict__ qv, const float* __restrict__ qa,
                 const float* __restrict__ kv, const float* __restrict__ ka,
                 const float* __restrict__ xv, const float* __restrict__ xa,
                 float* __restrict__ o_va, float* __restrict__ o_v,
                 float* __restrict__ o_av, float* __restrict__ o_a)
{
    const int b    = blockIdx.x;
    const int tid  = threadIdx.x;
    const int wave = tid >> 6;
    const int lane = tid & 63;
    __shared__ float att[4][3][3];
    const size_t base = (size_t)b * 768;
    const float* Qs[4] = {qv, qv, qa, qa};
    const float* Ks[4] = {ka, kv, kv, ka};
    const float* Xs[4] = {xa, xv, xv, xa};
    float*       Os[4] = {o_va, o_v, o_av, o_a};
    const float* q = Qs[wave] + base;
    const float* k = Ks[wave] + base;
    float part[9] = {};
    for (int d = lane; d < 256; d += 64) {
        float q0 = q[d], q1 = q[256 + d], q2 = q[512 + d];
        float k0 = k[d], k1 = k[256 + d], k2 = k[512 + d];
        part[0] += q0 * k0; part[1] += q0 * k1; part[2] += q0 * k2;
        part[3] += q1 * k0; part[4] += q1 * k1; part[5] += q1 * k2;
        part[6] += q2 * k0; part[7] += q2 * k1; part[8] += q2 * k2;
    }
    #pragma unroll
    for (int off = 32; off > 0; off >>= 1)
        #pragma unroll
        for (int i = 0; i < 9; i++) part[i] += __shfl_down(part[i], off);
    if (lane == 0) {
        #pragma unroll
        for (int s = 0; s < 3; s++) {
            float a0 = part[s * 3], a1 = part[s * 3 + 1], a2 = part[s * 3 + 2];
            float mx = fmaxf(a0, fmaxf(a1, a2));
            float e0 = expf(a0 - mx), e1 = expf(a1 - mx), e2 = expf(a2 - mx);
            float inv = NORM / (e0 + e1 + e2);
            att[wave][s][0] = e0 * inv;
            att[wave][s][1] = e1 * inv;
            att[wave][s][2] = e2 * inv;
        }
    }
    __syncthreads();
    const int d = tid; // 0..255
    #pragma unroll
    for (int w = 0; w < 4; w++) {
        const float* x = Xs[w] + base;
        float x0 = x[d], x1 = x[256 + d], x2 = x[512 + d];
        float* o = Os[w] + base;
        #pragma unroll
        for (int s = 0; s < 3; s++)
            o[s * 256 + d] = att[w][s][0] * x0 + att[w][s][1] * x1 + att[w][s][2] * x2;
    }
}

// ---------------- elementwise kernels --------------------------------------
__global__ void ew_c(const float* __restrict__ La, const float* __restrict__ Lb,
                     const float* __restrict__ alpha, float* __restrict__ out, int n)
{
    int i = blockIdx.x * 256 + threadIdx.x;
    if (i < n) {
        float v = (La[i] + Lb[i]) * alpha[i];
        out[i] = 1.f / (1.f + expf(-v));
    }
}

__global__ void ew_mix(const float* __restrict__ logits, const float* __restrict__ xv,
                       const float* __restrict__ xa, const float* __restrict__ bv,
                       const float* __restrict__ ba, const float* __restrict__ tc,
                       float* __restrict__ outv, float* __restrict__ outa, int n)
{
    int i = blockIdx.x * 256 + threadIdx.x;
    if (i < n) {
        float j = 1.f / (1.f + expf(-logits[i]));
        float M = tc[0] * j * xv[i] + (1.f - j) * xa[i];
        outv[i] = M * bv[i];
        outa[i] = M * ba[i];
    }
}

__global__ void fill0(float* __restrict__ p, int n)
{
    int i = blockIdx.x * 256 + threadIdx.x;
    if (i < n) p[i] = 0.f;
}

// ---------------------------------------------------------------------------
extern "C" void kernel_launch(void* const* d_in, const int* in_sizes, int n_in,
                              void* d_out, int out_size, void* d_ws, size_t ws_size,
                              hipStream_t stream)
{
    const float* img    = (const float*)d_in[0];
    const float* audio  = (const float*)d_in[1];
    const float* vis_W  = (const float*)d_in[2];
    const float* vis_b  = (const float*)d_in[3];
    const float* aud_W  = (const float*)d_in[4];
    const float* aud_b  = (const float*)d_in[5];
    const float* msv_W  = (const float*)d_in[6];
    const float* msv_b  = (const float*)d_in[7];
    const float* msa_W  = (const float*)d_in[8];
    const float* msa_b  = (const float*)d_in[9];
    const float* mmfa_W = (const float*)d_in[10];
    const float* mmfa_b = (const float*)d_in[11];
    const float* bil_W  = (const float*)d_in[12];
    const float* t_c    = (const float*)d_in[13];
    const float* out_W1 = (const float*)d_in[14];
    const float* out_b1 = (const float*)d_in[15];
    const float* out_W2 = (const float*)d_in[16];
    const float* out_b2 = (const float*)d_in[17];
    const float* clsv_W1 = (const float*)d_in[18];
    const float* clsv_W2 = (const float*)d_in[19];
    const float* clsa_W1 = (const float*)d_in[20];
    const float* clsa_W2 = (const float*)d_in[21];
    float* out = (float*)d_out;
    float* ws  = (float*)d_ws;

    // workspace layout (floats); total 13,664,256 floats = 54.7 MB
    constexpr size_t SD = 3072 * 256; // 786432
    float* vis  = ws;                      // 1024*1024
    float* aud  = vis + 1024 * 1024;       // 1024*1024
    float* v_ms = aud + 1024 * 1024;       // SD
    float* a_ms = v_ms + SD;
    float* x_v2 = a_ms + SD;
    float* x_a2 = x_v2 + SD;
    float* ovb  = x_a2 + SD;
    float* oab  = ovb + SD;
    float* q_v  = oab + SD;  float* LA     = q_v;   // reuse after attention
    float* q_a  = q_v + SD;  float* LB     = q_a;
    float* k_v  = q_a + SD;  float* c_va   = k_v;
    float* k_a  = k_v + SD;  float* c_av   = k_a;
    float* a_va = k_a + SD;  float* logits = a_va;  // reuse after L4 gemm
    float* a_v  = a_va + SD;
    float* a_av = a_v + SD;
    float* a_a  = a_av + SD;
    float* hv   = a_a + SD;                // 1024*512
    float* hc   = hv + 1024 * 512;         // 1024*32

    auto gemm = [&](const float* A, const float* W, const float* bias, float* C,
                    int M, int N, int K, int act) {
        dim3 g((N + 63) / 64, (M + 63) / 64);
        if (act) gemm_bt<1><<<g, 256, 0, stream>>>(A, W, bias, C, M, N, K);
        else     gemm_bt<0><<<g, 256, 0, stream>>>(A, W, bias, C, M, N, K);
    };

    // encoders + multiscale
    gemm(img,   vis_W, vis_b, vis, 1024, 1024, 4096, 1);
    gemm(audio, aud_W, aud_b, aud, 1024, 1024, 1024, 1);
    gemm(vis, msv_W, msv_b, v_ms, 1024, 768, 1024, 1);
    gemm(aud, msa_W, msa_b, a_ms, 1024, 768, 1024, 1);

    const int EW_N = (int)SD;
    const int EW_G = (EW_N + 255) / 256;

    auto mmfa = [&](const float* xv, const float* xa, float* outv, float* outa) {
        gemm(xv, mmfa_W + 0 * 65536, mmfa_b + 0 * 256, q_v, 3072, 256, 256, 0);
        gemm(xa, mmfa_W + 1 * 65536, mmfa_b + 1 * 256, q_a, 3072, 256, 256, 0);
        gemm(xv, mmfa_W + 2 * 65536, mmfa_b + 2 * 256, k_v, 3072, 256, 256, 0);
        gemm(xa, mmfa_W + 3 * 65536, mmfa_b + 3 * 256, k_a, 3072, 256, 256, 0);
        attn_kernel<<<1024, 256, 0, stream>>>(q_v, q_a, k_v, k_a, xv, xa,
                                              a_va, a_v, a_av, a_a);
        gemm(a_va, mmfa_W + 4 * 65536, mmfa_b + 4 * 256, LA, 3072, 256, 256, 0);
        gemm(a_v,  mmfa_W + 5 * 65536, mmfa_b + 5 * 256, LB, 3072, 256, 256, 0);
        ew_c<<<EW_G, 256, 0, stream>>>(LA, LB, a_v, c_va, EW_N);
        gemm(a_av, mmfa_W + 6 * 65536, mmfa_b + 6 * 256, LA, 3072, 256, 256, 0);
        gemm(a_a,  mmfa_W + 7 * 65536, mmfa_b + 7 * 256, LB, 3072, 256, 256, 0);
        ew_c<<<EW_G, 256, 0, stream>>>(LA, LB, a_a, c_av, EW_N);
        fill0<<<EW_G, 256, 0, stream>>>(logits, EW_N);
        bilinear_bt<<<dim3(4, 48, 8), 256, 0, stream>>>(c_va, c_av, bil_W, logits);
        ew_mix<<<EW_G, 256, 0, stream>>>(logits, xv, xa, v_ms, a_ms, t_c,
                                         outv, outa, EW_N);
    };

    mmfa(v_ms, a_ms, x_v2, x_a2);   // M1 stage -> x_v2 = M1*v_ms, x_a2 = M1*a_ms
    mmfa(x_v2, x_a2, ovb, oab);     // M2 stage -> ov = M2*v_ms, oa = M2*a_ms

    // out_layer + classifiers; fv/fa written straight into d_out
    float* fv = out;
    float* fa = out + 1024 * 128;
    float* pv = out + 2 * 1024 * 128;
    float* pa = pv + 1024 * 10;

    gemm(ovb, out_W1, out_b1, hv, 1024, 512, 768, 1);
    gemm(hv,  out_W2, out_b2, fv, 1024, 128, 512, 0);
    gemm(oab, out_W1, out_b1, hv, 1024, 512, 768, 1);
    gemm(hv,  out_W2, out_b2, fa, 1024, 128, 512, 0);

    gemm(fv, clsv_W1, nullptr, hc, 1024, 32, 128, 1);
    gemm(hc, clsv_W2, nullptr, pv, 1024, 10, 32, 0);
    gemm(fa, clsa_W1, nullptr, hc, 1024, 32, 128, 1);
    gemm(hc, clsa_W2, nullptr, pa, 1024, 10, 32, 0);

    (void)in_sizes; (void)n_in; (void)out_size; (void)ws_size;
}

// Round 2
// 3607.143 us; speedup vs baseline: 1.6946x; 1.6946x over previous
//
#include <hip/hip_runtime.h>
#include <math.h>

// ---------------------------------------------------------------------------
// CrossModal_NN — round 2: bf16 MFMA bilinear.
// out[m,o] = sum_i cva[m,i] * (sum_j cav[m,j] * W[o,i,j])
//   inner GEMM per i0 (K=256) via mfma_f32_16x16x32_bf16, P-acc in regs,
//   per-i0 epilogue F += cva[:,i0] * P. cav tile in LDS (pad-8, 2-way free),
//   W bf16 B-frags loaded straight from global (L2-resident slices).
// W_bf16 (33.55 MB) aliases the q/k/alpha/vis/aud scratch region which is
// dead during the bilinear; converted once per mmfa stage.
// Total ws footprint: 54.0 MB (<= 54.7 MB proven in round 1).
// ---------------------------------------------------------------------------

typedef short short8   __attribute__((ext_vector_type(8)));
typedef float floatx4  __attribute__((ext_vector_type(4)));

constexpr float NORM = 0.0625f; // 1/sqrt(256), applied AFTER softmax (faithful)

__device__ __forceinline__ unsigned short f2bf(float f) {
    union { float f; unsigned int u; } v; v.f = f;
    unsigned int r = v.u + 0x7fffu + ((v.u >> 16) & 1u); // RNE
    return (unsigned short)(r >> 16);
}

// ---------------- generic fp32 GEMM: C = act(A @ W^T + bias) ---------------
template<int ACT>
__global__ __launch_bounds__(256)
void gemm_bt(const float* __restrict__ A, const float* __restrict__ W,
             const float* __restrict__ bias, float* __restrict__ C,
             int M, int N, int K)
{
    __shared__ __align__(16) float sA[32][68];
    __shared__ __align__(16) float sB[32][68];
    const int tid = threadIdx.x;
    const int m0 = blockIdx.y * 64;
    const int n0 = blockIdx.x * 64;
    const int tx = tid & 15;
    const int ty = tid >> 4;
    const int kk = tid & 31;
    const int rr = tid >> 5;
    float acc[4][4] = {};
    for (int k0 = 0; k0 < K; k0 += 32) {
        #pragma unroll
        for (int p = 0; p < 8; p++) {
            int mm = rr + p * 8;
            int m  = m0 + mm;
            int k  = k0 + kk;
            sA[kk][mm] = (m < M && k < K) ? A[(size_t)m * K + k] : 0.f;
        }
        #pragma unroll
        for (int p = 0; p < 8; p++) {
            int nn = rr + p * 8;
            int n  = n0 + nn;
            int k  = k0 + kk;
            sB[kk][nn] = (n < N && k < K) ? W[(size_t)n * K + k] : 0.f;
        }
        __syncthreads();
        #pragma unroll
        for (int q = 0; q < 32; q++) {
            float av[4], bv[4];
            #pragma unroll
            for (int i = 0; i < 4; i++) av[i] = sA[q][ty * 4 + i];
            #pragma unroll
            for (int j = 0; j < 4; j++) bv[j] = sB[q][tx * 4 + j];
            #pragma unroll
            for (int i = 0; i < 4; i++)
                #pragma unroll
                for (int j = 0; j < 4; j++)
                    acc[i][j] += av[i] * bv[j];
        }
        __syncthreads();
    }
    #pragma unroll
    for (int i = 0; i < 4; i++) {
        int m = m0 + ty * 4 + i;
        if (m >= M) continue;
        #pragma unroll
        for (int j = 0; j < 4; j++) {
            int n = n0 + tx * 4 + j;
            if (n >= N) continue;
            float v = acc[i][j];
            if (bias) v += bias[n];
            if (ACT) v = fmaxf(v, 0.f);
            C[(size_t)m * N + n] = v;
        }
    }
}

// ---------------- fp32 -> bf16 bulk convert (bil_W) -------------------------
__global__ __launch_bounds__(256)
void conv_w(const float* __restrict__ src, unsigned short* __restrict__ dst, int n)
{
    int i = (blockIdx.x * 256 + threadIdx.x) * 8;
    if (i + 7 < n) {
        float4 a = *(const float4*)(src + i);
        float4 b = *(const float4*)(src + i + 4);
        union { unsigned short s[8]; uint4 v; } o;
        o.s[0] = f2bf(a.x); o.s[1] = f2bf(a.y); o.s[2] = f2bf(a.z); o.s[3] = f2bf(a.w);
        o.s[4] = f2bf(b.x); o.s[5] = f2bf(b.y); o.s[6] = f2bf(b.z); o.s[7] = f2bf(b.w);
        *(uint4*)(dst + i) = o.v;
    }
}

// ---------------- bilinear MFMA --------------------------------------------
// grid (48 m-tiles, 8 k-splits), 256 threads (4 waves). Block tile M64 x N256,
// wave tile 64x64. Each block handles 32 i0-blocks (K-chunk 8192).
__global__ __launch_bounds__(256, 2)
void bilinear_mfma(const unsigned short* __restrict__ cav, // [3072][256] bf16
                   const float* __restrict__ cva,          // [3072][256] f32
                   const unsigned short* __restrict__ Wb,  // [256][65536] bf16
                   float* __restrict__ outp)               // [3072][256] f32
{
    __shared__ short sCav[64][264];   // pad 8 bf16 -> 2-way (free) b128 reads
    const int tid  = threadIdx.x;
    const int wave = tid >> 6, lane = tid & 63;
    const int quad = lane >> 4, l15 = lane & 15;
    const int m0   = blockIdx.x * 64;
    const int n0w  = wave * 64;
    const int z0   = blockIdx.y * 32;   // i0 in [z0, z0+32)

    // stage cav tile: 64 rows x 256 bf16
    {
        int r = tid >> 2, seg = tid & 3;
        const unsigned short* src = cav + (size_t)(m0 + r) * 256 + seg * 64;
        #pragma unroll
        for (int u = 0; u < 8; u++)
            *(short8*)&sCav[r][seg * 64 + u * 8] = *(const short8*)(src + u * 8);
    }
    __syncthreads();

    floatx4 F[4][4];
    #pragma unroll
    for (int f = 0; f < 4; f++)
        #pragma unroll
        for (int g = 0; g < 4; g++)
            F[f][g] = (floatx4){0.f, 0.f, 0.f, 0.f};

    for (int ib = 0; ib < 32; ib++) {
        const int i0 = z0 + ib;
        float sv[4][4];
        #pragma unroll
        for (int f = 0; f < 4; f++)
            #pragma unroll
            for (int r = 0; r < 4; r++)
                sv[f][r] = cva[(size_t)(m0 + 16 * f + quad * 4 + r) * 256 + i0];

        floatx4 P[4][4];
        #pragma unroll
        for (int f = 0; f < 4; f++)
            #pragma unroll
            for (int g = 0; g < 4; g++)
                P[f][g] = (floatx4){0.f, 0.f, 0.f, 0.f};

        #pragma unroll
        for (int s = 0; s < 8; s++) {
            short8 a[4], b[4];
            #pragma unroll
            for (int f = 0; f < 4; f++)
                a[f] = *(const short8*)&sCav[16 * f + l15][s * 32 + quad * 8];
            #pragma unroll
            for (int g = 0; g < 4; g++)
                b[g] = *(const short8*)(Wb + (size_t)(n0w + 16 * g + l15) * 65536
                                           + (size_t)i0 * 256 + s * 32 + quad * 8);
            #pragma unroll
            for (int f = 0; f < 4; f++)
                #pragma unroll
                for (int g = 0; g < 4; g++)
                    P[f][g] = __builtin_amdgcn_mfma_f32_16x16x32_bf16(a[f], b[g], P[f][g], 0, 0, 0);
        }
        #pragma unroll
        for (int f = 0; f < 4; f++)
            #pragma unroll
            for (int g = 0; g < 4; g++)
                #pragma unroll
                for (int r = 0; r < 4; r++)
                    F[f][g][r] += sv[f][r] * P[f][g][r];
    }
    #pragma unroll
    for (int f = 0; f < 4; f++)
        #pragma unroll
        for (int g = 0; g < 4; g++)
            #pragma unroll
            for (int r = 0; r < 4; r++)
                atomicAdd(&outp[(size_t)(m0 + 16 * f + quad * 4 + r) * 256
                                + n0w + 16 * g + l15], F[f][g][r]);
}

// ---------------- attention -------------------------------------------------
__global__ __launch_bounds__(256)
void attn_kernel(const float* __restrict__ qv, const float* __restrict__ qa,
                 const float* __restrict__ kv, const float* __restrict__ ka,
                 const float* __restrict__ xv, const float* __restrict__ xa,
                 float* __restrict__ o_va, float* __restrict__ o_v,
                 float* __restrict__ o_av, float* __restrict__ o_a)
{
    const int b    = blockIdx.x;
    const int tid  = threadIdx.x;
    const int wave = tid >> 6;
    const int lane = tid & 63;
    __shared__ float att[4][3][3];
    const size_t base = (size_t)b * 768;
    const float* Qs[4] = {qv, qv, qa, qa};
    const float* Ks[4] = {ka, kv, kv, ka};
    const float* Xs[4] = {xa, xv, xv, xa};
    float*       Os[4] = {o_va, o_v, o_av, o_a};
    const float* q = Qs[wave] + base;
    const float* k = Ks[wave] + base;
    float part[9] = {};
    for (int d = lane; d < 256; d += 64) {
        float q0 = q[d], q1 = q[256 + d], q2 = q[512 + d];
        float k0 = k[d], k1 = k[256 + d], k2 = k[512 + d];
        part[0] += q0 * k0; part[1] += q0 * k1; part[2] += q0 * k2;
        part[3] += q1 * k0; part[4] += q1 * k1; part[5] += q1 * k2;
        part[6] += q2 * k0; part[7] += q2 * k1; part[8] += q2 * k2;
    }
    #pragma unroll
    for (int off = 32; off > 0; off >>= 1)
        #pragma unroll
        for (int i = 0; i < 9; i++) part[i] += __shfl_down(part[i], off);
    if (lane == 0) {
        #pragma unroll
        for (int s = 0; s < 3; s++) {
            float a0 = part[s * 3], a1 = part[s * 3 + 1], a2 = part[s * 3 + 2];
            float mx = fmaxf(a0, fmaxf(a1, a2));
            float e0 = expf(a0 - mx), e1 = expf(a1 - mx), e2 = expf(a2 - mx);
            float inv = NORM / (e0 + e1 + e2);
            att[wave][s][0] = e0 * inv;
            att[wave][s][1] = e1 * inv;
            att[wave][s][2] = e2 * inv;
        }
    }
    __syncthreads();
    const int d = tid;
    #pragma unroll
    for (int w = 0; w < 4; w++) {
        const float* x = Xs[w] + base;
        float x0 = x[d], x1 = x[256 + d], x2 = x[512 + d];
        float* o = Os[w] + base;
        #pragma unroll
        for (int s = 0; s < 3; s++)
            o[s * 256 + d] = att[w][s][0] * x0 + att[w][s][1] * x1 + att[w][s][2] * x2;
    }
}

// ---------------- elementwise ----------------------------------------------
__global__ void ew_c_f32(const float* __restrict__ La, const float* __restrict__ Lb,
                         const float* __restrict__ alpha, float* __restrict__ out, int n)
{
    int i = blockIdx.x * 256 + threadIdx.x;
    if (i < n) {
        float v = (La[i] + Lb[i]) * alpha[i];
        out[i] = 1.f / (1.f + expf(-v));
    }
}

__global__ void ew_c_bf16(const float* __restrict__ La, const float* __restrict__ Lb,
                          const float* __restrict__ alpha, unsigned short* __restrict__ out, int n)
{
    int i = blockIdx.x * 256 + threadIdx.x;
    if (i < n) {
        float v = (La[i] + Lb[i]) * alpha[i];
        out[i] = f2bf(1.f / (1.f + expf(-v)));
    }
}

__global__ void ew_mix(const float* __restrict__ logits, const float* __restrict__ xv,
                       const float* __restrict__ xa, const float* __restrict__ bv,
                       const float* __restrict__ ba, const float* __restrict__ tc,
                       float* __restrict__ outv, float* __restrict__ outa, int n)
{
    int i = blockIdx.x * 256 + threadIdx.x;
    if (i < n) {
        float j = 1.f / (1.f + expf(-logits[i]));
        float M = tc[0] * j * xv[i] + (1.f - j) * xa[i];
        outv[i] = M * bv[i];
        outa[i] = M * ba[i];
    }
}

__global__ void fill0(float* __restrict__ p, int n)
{
    int i = blockIdx.x * 256 + threadIdx.x;
    if (i < n) p[i] = 0.f;
}

// ---------------------------------------------------------------------------
extern "C" void kernel_launch(void* const* d_in, const int* in_sizes, int n_in,
                              void* d_out, int out_size, void* d_ws, size_t ws_size,
                              hipStream_t stream)
{
    const float* img    = (const float*)d_in[0];
    const float* audio  = (const float*)d_in[1];
    const float* vis_W  = (const float*)d_in[2];
    const float* vis_b  = (const float*)d_in[3];
    const float* aud_W  = (const float*)d_in[4];
    const float* aud_b  = (const float*)d_in[5];
    const float* msv_W  = (const float*)d_in[6];
    const float* msv_b  = (const float*)d_in[7];
    const float* msa_W  = (const float*)d_in[8];
    const float* msa_b  = (const float*)d_in[9];
    const float* mmfa_W = (const float*)d_in[10];
    const float* mmfa_b = (const float*)d_in[11];
    const float* bil_W  = (const float*)d_in[12];
    const float* t_c    = (const float*)d_in[13];
    const float* out_W1 = (const float*)d_in[14];
    const float* out_b1 = (const float*)d_in[15];
    const float* out_W2 = (const float*)d_in[16];
    const float* out_b2 = (const float*)d_in[17];
    const float* clsv_W1 = (const float*)d_in[18];
    const float* clsv_W2 = (const float*)d_in[19];
    const float* clsa_W1 = (const float*)d_in[20];
    const float* clsa_W2 = (const float*)d_in[21];
    float* out = (float*)d_out;
    float* ws  = (float*)d_ws;

    constexpr size_t SD = 3072 * 256; // 786432
    // ---- scratch region S (8,388,608 floats = 33.55 MB), aliased by W_bf16
    float* S    = ws;
    float* vis  = S;                      // 1,048,576
    float* aud  = S + 1048576;            // 1,048,576
    float* q_v  = S + 2097152;
    float* q_a  = q_v + SD;
    float* k_v  = q_a + SD;
    float* k_a  = k_v + SD;
    float* a_va = k_a + SD;
    float* a_v  = a_va + SD;
    float* a_av = a_v + SD;
    float* a_a  = a_av + SD;              // ends at S + 8,388,608
    unsigned short* Wbf = (unsigned short*)S;  // 16,777,216 bf16 over all of S
    float* LA = q_v; float* LB = q_a;     // alias (q dead after attn)
    float* ovb = S;                       // stage-2 outputs (S dead then)
    float* oab = S + SD;
    float* hv  = S + 2 * SD;              // 524,288
    float* hc  = hv + 524288;             // 32,768
    // ---- persistent region
    float* P0     = ws + 8388608;
    float* v_ms   = P0;
    float* a_ms   = v_ms + SD;
    float* x_v2   = a_ms + SD;
    float* x_a2   = x_v2 + SD;
    float* logits = x_a2 + SD;
    float* c_va   = logits + SD;                    // fp32
    unsigned short* c_av = (unsigned short*)(c_va + SD); // bf16
    // total: 13,500,416 floats = 54.0 MB

    auto gemm = [&](const float* A, const float* W, const float* bias, float* C,
                    int M, int N, int K, int act) {
        dim3 g((N + 63) / 64, (M + 63) / 64);
        if (act) gemm_bt<1><<<g, 256, 0, stream>>>(A, W, bias, C, M, N, K);
        else     gemm_bt<0><<<g, 256, 0, stream>>>(A, W, bias, C, M, N, K);
    };

    // encoders + multiscale
    gemm(img,   vis_W, vis_b, vis, 1024, 1024, 4096, 1);
    gemm(audio, aud_W, aud_b, aud, 1024, 1024, 1024, 1);
    gemm(vis, msv_W, msv_b, v_ms, 1024, 768, 1024, 1);
    gemm(aud, msa_W, msa_b, a_ms, 1024, 768, 1024, 1);

    const int EW_N = (int)SD;
    const int EW_G = (EW_N + 255) / 256;

    auto mmfa = [&](const float* xv, const float* xa, float* outv, float* outa) {
        gemm(xv, mmfa_W + 0 * 65536, mmfa_b + 0 * 256, q_v, 3072, 256, 256, 0);
        gemm(xa, mmfa_W + 1 * 65536, mmfa_b + 1 * 256, q_a, 3072, 256, 256, 0);
        gemm(xv, mmfa_W + 2 * 65536, mmfa_b + 2 * 256, k_v, 3072, 256, 256, 0);
        gemm(xa, mmfa_W + 3 * 65536, mmfa_b + 3 * 256, k_a, 3072, 256, 256, 0);
        attn_kernel<<<1024, 256, 0, stream>>>(q_v, q_a, k_v, k_a, xv, xa,
                                              a_va, a_v, a_av, a_a);
        gemm(a_va, mmfa_W + 4 * 65536, mmfa_b + 4 * 256, LA, 3072, 256, 256, 0);
        gemm(a_v,  mmfa_W + 5 * 65536, mmfa_b + 5 * 256, LB, 3072, 256, 256, 0);
        ew_c_f32<<<EW_G, 256, 0, stream>>>(LA, LB, a_v, c_va, EW_N);
        gemm(a_av, mmfa_W + 6 * 65536, mmfa_b + 6 * 256, LA, 3072, 256, 256, 0);
        gemm(a_a,  mmfa_W + 7 * 65536, mmfa_b + 7 * 256, LB, 3072, 256, 256, 0);
        ew_c_bf16<<<EW_G, 256, 0, stream>>>(LA, LB, a_a, c_av, EW_N);
        // q/k/alpha/vis/aud all dead now: overwrite S with bf16 W
        conv_w<<<8192, 256, 0, stream>>>(bil_W, Wbf, 16777216);
        fill0<<<EW_G, 256, 0, stream>>>(logits, EW_N);
        bilinear_mfma<<<dim3(48, 8), 256, 0, stream>>>(c_av, c_va, Wbf, logits);
        ew_mix<<<EW_G, 256, 0, stream>>>(logits, xv, xa, v_ms, a_ms, t_c,
                                         outv, outa, EW_N);
    };

    mmfa(v_ms, a_ms, x_v2, x_a2);   // M1 stage
    mmfa(x_v2, x_a2, ovb, oab);     // M2 stage (outputs land in S)

    float* fv = out;
    float* fa = out + 1024 * 128;
    float* pv = out + 2 * 1024 * 128;
    float* pa = pv + 1024 * 10;

    gemm(ovb, out_W1, out_b1, hv, 1024, 512, 768, 1);
    gemm(hv,  out_W2, out_b2, fv, 1024, 128, 512, 0);
    gemm(oab, out_W1, out_b1, hv, 1024, 512, 768, 1);
    gemm(hv,  out_W2, out_b2, fa, 1024, 128, 512, 0);

    gemm(fv, clsv_W1, nullptr, hc, 1024, 32, 128, 1);
    gemm(hc, clsv_W2, nullptr, pv, 1024, 10, 32, 0);
    gemm(fa, clsa_W1, nullptr, hc, 1024, 32, 128, 1);
    gemm(hc, clsa_W2, nullptr, pa, 1024, 10, 32, 0);

    (void)in_sizes; (void)n_in; (void)out_size; (void)ws_size;
}

// Round 3
// 1270.416 us; speedup vs baseline: 4.8115x; 2.8393x over previous
//
#include <hip/hip_runtime.h>
#include <math.h>

// ---------------------------------------------------------------------------
// CrossModal_NN — round 3: all major GEMMs -> bf16 MFMA (fp32 accumulate).
// Fusions: q/k N-concat (one [3072,512,256] GEMM per modality),
//          lin4+lin5 / lin6+lin7 K-concat ([3072,256,512], add folded into K).
// Weights packed to bf16 once per launch; A converted fp32->bf16 in staging.
// Bilinear: c_va stored transposed bf16 -> vectorized short4 loads.
// ws: 53.48 MB (< 54.66 MB proven).
// ---------------------------------------------------------------------------

typedef short short8   __attribute__((ext_vector_type(8)));
typedef float floatx4  __attribute__((ext_vector_type(4)));

constexpr float NORM = 0.0625f; // 1/sqrt(256), applied AFTER softmax (faithful)

__device__ __forceinline__ unsigned short f2bf(float f) {
    union { float f; unsigned int u; } v; v.f = f;
    unsigned int r = v.u + 0x7fffu + ((v.u >> 16) & 1u); // RNE
    return (unsigned short)(r >> 16);
}
__device__ __forceinline__ float bf2f(unsigned short s) {
    union { unsigned int u; float f; } v; v.u = ((unsigned int)s) << 16;
    return v.f;
}

// ---------------- bf16 MFMA GEMM: C = act(A @ W^T + bias) -------------------
// A fp32 [M,K] (converted to bf16 in staging), W bf16 [N,K], C fp32 [M,N].
// M,N,K multiples of 64. Tile 64x64, BK=64, 4 waves (each 32x32).
template<int ACT>
__global__ __launch_bounds__(256)
void gemm_mfma(const float* __restrict__ A, const unsigned short* __restrict__ W,
               const float* __restrict__ bias, float* __restrict__ C,
               int M, int N, int K)
{
    __shared__ short sA[64][72];
    __shared__ short sW[64][72];
    const int tid  = threadIdx.x;
    const int wave = tid >> 6, lane = tid & 63;
    const int quad = lane >> 4, l15 = lane & 15;
    const int m0 = blockIdx.y * 64, n0 = blockIdx.x * 64;
    const int mw = (wave & 1) * 32, nw = (wave >> 1) * 32;
    const int srow = tid >> 2, sseg = tid & 3;

    floatx4 P[2][2];
    #pragma unroll
    for (int f = 0; f < 2; f++)
        #pragma unroll
        for (int g = 0; g < 2; g++)
            P[f][g] = (floatx4){0.f, 0.f, 0.f, 0.f};

    for (int k0 = 0; k0 < K; k0 += 64) {
        const float* ap = A + (size_t)(m0 + srow) * K + k0 + sseg * 16;
        float4 a0 = *(const float4*)(ap);
        float4 a1 = *(const float4*)(ap + 4);
        float4 a2 = *(const float4*)(ap + 8);
        float4 a3 = *(const float4*)(ap + 12);
        union { unsigned short s[8]; short8 v; } p0, p1;
        p0.s[0] = f2bf(a0.x); p0.s[1] = f2bf(a0.y); p0.s[2] = f2bf(a0.z); p0.s[3] = f2bf(a0.w);
        p0.s[4] = f2bf(a1.x); p0.s[5] = f2bf(a1.y); p0.s[6] = f2bf(a1.z); p0.s[7] = f2bf(a1.w);
        p1.s[0] = f2bf(a2.x); p1.s[1] = f2bf(a2.y); p1.s[2] = f2bf(a2.z); p1.s[3] = f2bf(a2.w);
        p1.s[4] = f2bf(a3.x); p1.s[5] = f2bf(a3.y); p1.s[6] = f2bf(a3.z); p1.s[7] = f2bf(a3.w);
        *(short8*)&sA[srow][sseg * 16]     = p0.v;
        *(short8*)&sA[srow][sseg * 16 + 8] = p1.v;
        const unsigned short* wp = W + (size_t)(n0 + srow) * K + k0 + sseg * 16;
        *(short8*)&sW[srow][sseg * 16]     = *(const short8*)wp;
        *(short8*)&sW[srow][sseg * 16 + 8] = *(const short8*)(wp + 8);
        __syncthreads();
        #pragma unroll
        for (int kh = 0; kh < 2; kh++) {
            short8 af[2], wf[2];
            af[0] = *(short8*)&sA[mw + l15][kh * 32 + quad * 8];
            af[1] = *(short8*)&sA[mw + 16 + l15][kh * 32 + quad * 8];
            wf[0] = *(short8*)&sW[nw + l15][kh * 32 + quad * 8];
            wf[1] = *(short8*)&sW[nw + 16 + l15][kh * 32 + quad * 8];
            #pragma unroll
            for (int f = 0; f < 2; f++)
                #pragma unroll
                for (int g = 0; g < 2; g++)
                    P[f][g] = __builtin_amdgcn_mfma_f32_16x16x32_bf16(af[f], wf[g], P[f][g], 0, 0, 0);
        }
        __syncthreads();
    }
    #pragma unroll
    for (int f = 0; f < 2; f++)
        #pragma unroll
        for (int g = 0; g < 2; g++)
            #pragma unroll
            for (int r = 0; r < 4; r++) {
                int m = m0 + mw + 16 * f + quad * 4 + r;
                int n = n0 + nw + 16 * g + l15;
                float v = P[f][g][r] + bias[n];
                if (ACT) v = fmaxf(v, 0.f);
                C[(size_t)m * N + n] = v;
            }
}

// ---------------- fp32 vector GEMM (kept for tiny classifier layers) --------
template<int ACT>
__global__ __launch_bounds__(256)
void gemm_bt(const float* __restrict__ A, const float* __restrict__ W,
             const float* __restrict__ bias, float* __restrict__ C,
             int M, int N, int K)
{
    __shared__ __align__(16) float sA[32][68];
    __shared__ __align__(16) float sB[32][68];
    const int tid = threadIdx.x;
    const int m0 = blockIdx.y * 64;
    const int n0 = blockIdx.x * 64;
    const int tx = tid & 15;
    const int ty = tid >> 4;
    const int kk = tid & 31;
    const int rr = tid >> 5;
    float acc[4][4] = {};
    for (int k0 = 0; k0 < K; k0 += 32) {
        #pragma unroll
        for (int p = 0; p < 8; p++) {
            int mm = rr + p * 8;
            int m  = m0 + mm;
            int k  = k0 + kk;
            sA[kk][mm] = (m < M && k < K) ? A[(size_t)m * K + k] : 0.f;
        }
        #pragma unroll
        for (int p = 0; p < 8; p++) {
            int nn = rr + p * 8;
            int n  = n0 + nn;
            int k  = k0 + kk;
            sB[kk][nn] = (n < N && k < K) ? W[(size_t)n * K + k] : 0.f;
        }
        __syncthreads();
        #pragma unroll
        for (int q = 0; q < 32; q++) {
            float av[4], bv[4];
            #pragma unroll
            for (int i = 0; i < 4; i++) av[i] = sA[q][ty * 4 + i];
            #pragma unroll
            for (int j = 0; j < 4; j++) bv[j] = sB[q][tx * 4 + j];
            #pragma unroll
            for (int i = 0; i < 4; i++)
                #pragma unroll
                for (int j = 0; j < 4; j++)
                    acc[i][j] += av[i] * bv[j];
        }
        __syncthreads();
    }
    #pragma unroll
    for (int i = 0; i < 4; i++) {
        int m = m0 + ty * 4 + i;
        if (m >= M) continue;
        #pragma unroll
        for (int j = 0; j < 4; j++) {
            int n = n0 + tx * 4 + j;
            if (n >= N) continue;
            float v = acc[i][j];
            if (bias) v += bias[n];
            if (ACT) v = fmaxf(v, 0.f);
            C[(size_t)m * N + n] = v;
        }
    }
}

// ---------------- fp32 -> bf16 bulk convert ---------------------------------
__global__ __launch_bounds__(256)
void conv_w(const float* __restrict__ src, unsigned short* __restrict__ dst, int n)
{
    int i = (blockIdx.x * 256 + threadIdx.x) * 8;
    if (i + 7 < n) {
        float4 a = *(const float4*)(src + i);
        float4 b = *(const float4*)(src + i + 4);
        union { unsigned short s[8]; uint4 v; } o;
        o.s[0] = f2bf(a.x); o.s[1] = f2bf(a.y); o.s[2] = f2bf(a.z); o.s[3] = f2bf(a.w);
        o.s[4] = f2bf(b.x); o.s[5] = f2bf(b.y); o.s[6] = f2bf(b.z); o.s[7] = f2bf(b.w);
        *(uint4*)(dst + i) = o.v;
    }
}

// K-concat pack: Wcva[o][0:256]=W4[o], [256:512]=W5[o]; same for Wcav from W6,W7
__global__ __launch_bounds__(256)
void pack_kcat(const float* __restrict__ mW, unsigned short* __restrict__ Wcva,
               unsigned short* __restrict__ Wcav)
{
    int i = blockIdx.x * 256 + threadIdx.x; // 65536
    int row = i >> 8, col = i & 255;
    Wcva[row * 512 + col]       = f2bf(mW[4 * 65536 + i]);
    Wcva[row * 512 + 256 + col] = f2bf(mW[5 * 65536 + i]);
    Wcav[row * 512 + col]       = f2bf(mW[6 * 65536 + i]);
    Wcav[row * 512 + 256 + col] = f2bf(mW[7 * 65536 + i]);
}

__global__ __launch_bounds__(256)
void pack_bias(const float* __restrict__ mb, float* __restrict__ bqkv,
               float* __restrict__ bqka, float* __restrict__ bcva,
               float* __restrict__ bcav)
{
    int i = blockIdx.x * 256 + threadIdx.x; // 512
    int c = i & 255;
    bqkv[i] = mb[(i < 256 ? 0 : 512) + c];
    bqka[i] = mb[(i < 256 ? 256 : 768) + c];
    if (i < 256) {
        bcva[i] = mb[4 * 256 + i] + mb[5 * 256 + i];
        bcav[i] = mb[6 * 256 + i] + mb[7 * 256 + i];
    }
}

// ---------------- bilinear MFMA --------------------------------------------
// out[m,o] += sum_i cvaT[i,m] * (sum_j cav[m,j]*W[o,i*256+j]); grid (48, 8).
__global__ __launch_bounds__(256, 2)
void bilinear_mfma(const unsigned short* __restrict__ cav,  // [3072][256] bf16
                   const unsigned short* __restrict__ cvaT, // [256][3072] bf16
                   const unsigned short* __restrict__ Wb,   // [256][65536] bf16
                   float* __restrict__ outp)                // [3072][256] f32
{
    __shared__ short sCav[64][264];
    const int tid  = threadIdx.x;
    const int wave = tid >> 6, lane = tid & 63;
    const int quad = lane >> 4, l15 = lane & 15;
    const int m0   = blockIdx.x * 64;
    const int n0w  = wave * 64;
    const int z0   = blockIdx.y * 32;

    {
        int r = tid >> 2, seg = tid & 3;
        const unsigned short* src = cav + (size_t)(m0 + r) * 256 + seg * 64;
        #pragma unroll
        for (int u = 0; u < 8; u++)
            *(short8*)&sCav[r][seg * 64 + u * 8] = *(const short8*)(src + u * 8);
    }
    __syncthreads();

    floatx4 F[4][4];
    #pragma unroll
    for (int f = 0; f < 4; f++)
        #pragma unroll
        for (int g = 0; g < 4; g++)
            F[f][g] = (floatx4){0.f, 0.f, 0.f, 0.f};

    for (int ib = 0; ib < 32; ib++) {
        const int i0 = z0 + ib;
        float sv[4][4];
        #pragma unroll
        for (int f = 0; f < 4; f++) {
            uint2 raw = *(const uint2*)(cvaT + (size_t)i0 * 3072 + m0 + 16 * f + quad * 4);
            sv[f][0] = bf2f((unsigned short)(raw.x & 0xffff));
            sv[f][1] = bf2f((unsigned short)(raw.x >> 16));
            sv[f][2] = bf2f((unsigned short)(raw.y & 0xffff));
            sv[f][3] = bf2f((unsigned short)(raw.y >> 16));
        }
        floatx4 P[4][4];
        #pragma unroll
        for (int f = 0; f < 4; f++)
            #pragma unroll
            for (int g = 0; g < 4; g++)
                P[f][g] = (floatx4){0.f, 0.f, 0.f, 0.f};
        #pragma unroll
        for (int s = 0; s < 8; s++) {
            short8 a[4], b[4];
            #pragma unroll
            for (int f = 0; f < 4; f++)
                a[f] = *(const short8*)&sCav[16 * f + l15][s * 32 + quad * 8];
            #pragma unroll
            for (int g = 0; g < 4; g++)
                b[g] = *(const short8*)(Wb + (size_t)(n0w + 16 * g + l15) * 65536
                                           + (size_t)i0 * 256 + s * 32 + quad * 8);
            #pragma unroll
            for (int f = 0; f < 4; f++)
                #pragma unroll
                for (int g = 0; g < 4; g++)
                    P[f][g] = __builtin_amdgcn_mfma_f32_16x16x32_bf16(a[f], b[g], P[f][g], 0, 0, 0);
        }
        #pragma unroll
        for (int f = 0; f < 4; f++)
            #pragma unroll
            for (int g = 0; g < 4; g++)
                #pragma unroll
                for (int r = 0; r < 4; r++)
                    F[f][g][r] += sv[f][r] * P[f][g][r];
    }
    #pragma unroll
    for (int f = 0; f < 4; f++)
        #pragma unroll
        for (int g = 0; g < 4; g++)
            #pragma unroll
            for (int r = 0; r < 4; r++)
                atomicAdd(&outp[(size_t)(m0 + 16 * f + quad * 4 + r) * 256
                                + n0w + 16 * g + l15], F[f][g][r]);
}

// ---------------- attention (packed q/k [3072][512], packed alpha out) ------
__global__ __launch_bounds__(256)
void attn_packed(const float* __restrict__ qkv, const float* __restrict__ qka,
                 const float* __restrict__ xv, const float* __restrict__ xa,
                 float* __restrict__ al_v, float* __restrict__ al_a)
{
    const int b    = blockIdx.x;
    const int tid  = threadIdx.x;
    const int wave = tid >> 6;
    const int lane = tid & 63;
    __shared__ float att[4][3][3];
    const size_t b512 = (size_t)b * 1536;
    const size_t b768 = (size_t)b * 768;
    const float* Qs[4] = {qkv, qkv, qka, qka};
    const float* Ks[4] = {qka + 256, qkv + 256, qkv + 256, qka + 256};
    const float* Xs[4] = {xa, xv, xv, xa};
    float*       Os[4] = {al_v, al_v + 256, al_a, al_a + 256};
    const float* q = Qs[wave] + b512;
    const float* k = Ks[wave] + b512;
    float part[9] = {};
    for (int d = lane; d < 256; d += 64) {
        float q0 = q[d], q1 = q[512 + d], q2 = q[1024 + d];
        float k0 = k[d], k1 = k[512 + d], k2 = k[1024 + d];
        part[0] += q0 * k0; part[1] += q0 * k1; part[2] += q0 * k2;
        part[3] += q1 * k0; part[4] += q1 * k1; part[5] += q1 * k2;
        part[6] += q2 * k0; part[7] += q2 * k1; part[8] += q2 * k2;
    }
    #pragma unroll
    for (int off = 32; off > 0; off >>= 1)
        #pragma unroll
        for (int i = 0; i < 9; i++) part[i] += __shfl_down(part[i], off);
    if (lane == 0) {
        #pragma unroll
        for (int s = 0; s < 3; s++) {
            float a0 = part[s * 3], a1 = part[s * 3 + 1], a2 = part[s * 3 + 2];
            float mx = fmaxf(a0, fmaxf(a1, a2));
            float e0 = expf(a0 - mx), e1 = expf(a1 - mx), e2 = expf(a2 - mx);
            float inv = NORM / (e0 + e1 + e2);
            att[wave][s][0] = e0 * inv;
            att[wave][s][1] = e1 * inv;
            att[wave][s][2] = e2 * inv;
        }
    }
    __syncthreads();
    const int d = tid;
    #pragma unroll
    for (int w = 0; w < 4; w++) {
        const float* x = Xs[w] + b768;
        float x0 = x[d], x1 = x[256 + d], x2 = x[512 + d];
        float* o = Os[w] + b512;
        #pragma unroll
        for (int s = 0; s < 3; s++)
            o[s * 512 + d] = att[w][s][0] * x0 + att[w][s][1] * x1 + att[w][s][2] * x2;
    }
}

// ---------------- elementwise ----------------------------------------------
// c = sigmoid(Cg * alpha), alpha = packed[.,256:512]; TRANS: write transposed
template<int TRANS>
__global__ void ew_c(const float* __restrict__ Cg, const float* __restrict__ al,
                     unsigned short* __restrict__ outp, int n)
{
    int i = blockIdx.x * 256 + threadIdx.x;
    if (i < n) {
        int row = i >> 8, col = i & 255;
        float a = al[(size_t)row * 512 + 256 + col];
        float v = Cg[i] * a;
        unsigned short r = f2bf(1.f / (1.f + expf(-v)));
        if (TRANS) outp[(size_t)col * 3072 + row] = r;
        else       outp[i] = r;
    }
}

__global__ void ew_mix(const float* __restrict__ logits, const float* __restrict__ xv,
                       const float* __restrict__ xa, const float* __restrict__ bv,
                       const float* __restrict__ ba, const float* __restrict__ tc,
                       float* __restrict__ outv, float* __restrict__ outa, int n)
{
    int i = blockIdx.x * 256 + threadIdx.x;
    if (i < n) {
        float j = 1.f / (1.f + expf(-logits[i]));
        float M = tc[0] * j * xv[i] + (1.f - j) * xa[i];
        outv[i] = M * bv[i];
        outa[i] = M * ba[i];
    }
}

__global__ void fill0(float* __restrict__ p, int n)
{
    int i = blockIdx.x * 256 + threadIdx.x;
    if (i < n) p[i] = 0.f;
}

// ---------------------------------------------------------------------------
extern "C" void kernel_launch(void* const* d_in, const int* in_sizes, int n_in,
                              void* d_out, int out_size, void* d_ws, size_t ws_size,
                              hipStream_t stream)
{
    const float* img    = (const float*)d_in[0];
    const float* audio  = (const float*)d_in[1];
    const float* vis_W  = (const float*)d_in[2];
    const float* vis_b  = (const float*)d_in[3];
    const float* aud_W  = (const float*)d_in[4];
    const float* aud_b  = (const float*)d_in[5];
    const float* msv_W  = (const float*)d_in[6];
    const float* msv_b  = (const float*)d_in[7];
    const float* msa_W  = (const float*)d_in[8];
    const float* msa_b  = (const float*)d_in[9];
    const float* mmfa_W = (const float*)d_in[10];
    const float* mmfa_b = (const float*)d_in[11];
    const float* bil_W  = (const float*)d_in[12];
    const float* t_c    = (const float*)d_in[13];
    const float* out_W1 = (const float*)d_in[14];
    const float* out_b1 = (const float*)d_in[15];
    const float* out_W2 = (const float*)d_in[16];
    const float* out_b2 = (const float*)d_in[17];
    const float* clsv_W1 = (const float*)d_in[18];
    const float* clsv_W2 = (const float*)d_in[19];
    const float* clsa_W1 = (const float*)d_in[20];
    const float* clsa_W2 = (const float*)d_in[21];
    float* out = (float*)d_out;
    float* ws  = (float*)d_ws;

    constexpr size_t SD = 3072 * 256; // 786432
    // ---- scratch region S: 8,388,608 floats, fully aliased by Wbf during bilinear
    float* S = ws;
    unsigned short* visbf = (unsigned short*)(S + 2097152); // 4,194,304 sh
    unsigned short* audbf = (unsigned short*)(S + 4194304); // 1,048,576 sh
    unsigned short* msvbf = (unsigned short*)(S + 4718592); //   786,432 sh
    unsigned short* msabf = (unsigned short*)(S + 5111808); //   786,432 sh
    float* vis  = S;                  // [0, 1048576)
    float* aud  = S + 1048576;        // [1048576, 2097152)
    float* qkv  = S;                  // [0, 1572864)         per-stage
    float* qka  = S + 1572864;        // [1572864, 3145728)
    float* al_v = S + 3145728;        // [3145728, 4718592)
    float* al_a = S + 4718592;        // [4718592, 6291456)
    float* Cg   = S + 6291456;        // [6291456, 7077888)
    unsigned short* Wbf = (unsigned short*)S; // bilinear W, all of S
    float* ovb  = S;                  // end-phase
    float* oab  = S + SD;
    float* hv   = S + 2 * SD;                     // 524288
    float* hc   = S + 2 * SD + 524288;            // 32768
    unsigned short* W1bf = (unsigned short*)(S + 2 * SD + 557056); // 393,216 sh
    unsigned short* W2bf = W1bf + 393216;                          //  65,536 sh
    // ---- persistent region
    float* P = ws + 8388608;
    float* v_ms   = P;
    float* a_ms   = P + SD;
    float* x_v2   = P + 2 * SD;
    float* x_a2   = P + 3 * SD;
    float* logits = P + 4 * SD;
    unsigned short* c_vaT = (unsigned short*)(P + 5 * SD);            // [256][3072]
    unsigned short* c_av  = (unsigned short*)(P + 5 * SD + SD / 2);   // [3072][256]
    unsigned short* Wqkv  = (unsigned short*)(P + 6 * SD);            // 131072 sh
    unsigned short* Wqka  = Wqkv + 131072;
    unsigned short* Wcva  = Wqka + 131072;
    unsigned short* Wcav  = Wcva + 131072;
    float* bqkv = P + 6 * SD + 262144;
    float* bqka = bqkv + 512;
    float* bcva = bqka + 512;
    float* bcav = bcva + 256;
    // total: 13,370,880 floats = 53.48 MB

    auto gmf = [&](const float* A, const unsigned short* W, const float* bias,
                   float* C, int M, int N, int K, int act) {
        dim3 g(N / 64, M / 64);
        if (act) gemm_mfma<1><<<g, 256, 0, stream>>>(A, W, bias, C, M, N, K);
        else     gemm_mfma<0><<<g, 256, 0, stream>>>(A, W, bias, C, M, N, K);
    };
    auto gbt = [&](const float* A, const float* W, const float* bias, float* C,
                   int M, int N, int K, int act) {
        dim3 g((N + 63) / 64, (M + 63) / 64);
        if (act) gemm_bt<1><<<g, 256, 0, stream>>>(A, W, bias, C, M, N, K);
        else     gemm_bt<0><<<g, 256, 0, stream>>>(A, W, bias, C, M, N, K);
    };

    // ---- weight packing (once per launch)
    conv_w<<<2048, 256, 0, stream>>>(vis_W, visbf, 4194304);
    conv_w<<<512,  256, 0, stream>>>(aud_W, audbf, 1048576);
    conv_w<<<384,  256, 0, stream>>>(msv_W, msvbf, 786432);
    conv_w<<<384,  256, 0, stream>>>(msa_W, msabf, 786432);
    conv_w<<<32, 256, 0, stream>>>(mmfa_W + 0 * 65536, Wqkv, 65536);
    conv_w<<<32, 256, 0, stream>>>(mmfa_W + 2 * 65536, Wqkv + 65536, 65536);
    conv_w<<<32, 256, 0, stream>>>(mmfa_W + 1 * 65536, Wqka, 65536);
    conv_w<<<32, 256, 0, stream>>>(mmfa_W + 3 * 65536, Wqka + 65536, 65536);
    pack_kcat<<<256, 256, 0, stream>>>(mmfa_W, Wcva, Wcav);
    pack_bias<<<2, 256, 0, stream>>>(mmfa_b, bqkv, bqka, bcva, bcav);

    // ---- encoders + multiscale
    gmf(img,   visbf, vis_b, vis, 1024, 1024, 4096, 1);
    gmf(audio, audbf, aud_b, aud, 1024, 1024, 1024, 1);
    gmf(vis, msvbf, msv_b, v_ms, 1024, 768, 1024, 1);
    gmf(aud, msabf, msa_b, a_ms, 1024, 768, 1024, 1);

    const int EW_N = (int)SD;
    const int EW_G = (EW_N + 255) / 256;

    auto mmfa = [&](const float* xv, const float* xa, float* outv, float* outa) {
        gmf(xv, Wqkv, bqkv, qkv, 3072, 512, 256, 0);
        gmf(xa, Wqka, bqka, qka, 3072, 512, 256, 0);
        attn_packed<<<1024, 256, 0, stream>>>(qkv, qka, xv, xa, al_v, al_a);
        gmf(al_v, Wcva, bcva, Cg, 3072, 256, 512, 0);
        ew_c<1><<<EW_G, 256, 0, stream>>>(Cg, al_v, c_vaT, EW_N);
        gmf(al_a, Wcav, bcav, Cg, 3072, 256, 512, 0);
        ew_c<0><<<EW_G, 256, 0, stream>>>(Cg, al_a, c_av, EW_N);
        conv_w<<<8192, 256, 0, stream>>>(bil_W, Wbf, 16777216);
        fill0<<<EW_G, 256, 0, stream>>>(logits, EW_N);
        bilinear_mfma<<<dim3(48, 8), 256, 0, stream>>>(c_av, c_vaT, Wbf, logits);
        ew_mix<<<EW_G, 256, 0, stream>>>(logits, xv, xa, v_ms, a_ms, t_c,
                                         outv, outa, EW_N);
    };

    mmfa(v_ms, a_ms, x_v2, x_a2);   // M1 stage
    mmfa(x_v2, x_a2, ovb, oab);     // M2 stage (outputs land in S)

    float* fv = out;
    float* fa = out + 1024 * 128;
    float* pv = out + 2 * 1024 * 128;
    float* pa = pv + 1024 * 10;

    // ---- out_layer (bf16 MFMA) + classifiers (fp32, tiny)
    conv_w<<<192, 256, 0, stream>>>(out_W1, W1bf, 393216);
    conv_w<<<32,  256, 0, stream>>>(out_W2, W2bf, 65536);
    gmf(ovb, W1bf, out_b1, hv, 1024, 512, 768, 1);
    gmf(hv,  W2bf, out_b2, fv, 1024, 128, 512, 0);
    gmf(oab, W1bf, out_b1, hv, 1024, 512, 768, 1);
    gmf(hv,  W2bf, out_b2, fa, 1024, 128, 512, 0);

    gbt(fv, clsv_W1, nullptr, hc, 1024, 32, 128, 1);
    gbt(hc, clsv_W2, nullptr, pv, 1024, 10, 32, 0);
    gbt(fa, clsa_W1, nullptr, hc, 1024, 32, 128, 1);
    gbt(hc, clsa_W2, nullptr, pa, 1024, 10, 32, 0);

    (void)in_sizes; (void)n_in; (void)out_size; (void)ws_size;
}

// Round 4
// 994.920 us; speedup vs baseline: 6.1439x; 1.2769x over previous
//
#include <hip/hip_runtime.h>
#include <math.h>

// ---------------------------------------------------------------------------
// CrossModal_NN — round 4: bilinear restructured as column-per-block GEMM.
// out[m,o] = sum_i cva[m,i] * (sum_j W[o,i,j] * cav[m,j])
// Block (o, m-half): loads W_o ONCE (fp32->bf16 in-register, 32 A-frags in
// VGPRs), streams cav tiles through LDS as B-operand:
//   P2[i,m] = W_o · cav^T  (MFMA, i on C-row axis -> cheap i-reduction)
//   outT[o,m] = sum_i cva[m,i]*P2[i,m]  (in-lane FMA + 2 shfl_xor + LDS sum)
// No atomics, no logits zero-fill, no bil_W pre-conversion.
// ---------------------------------------------------------------------------

typedef short short8   __attribute__((ext_vector_type(8)));
typedef float floatx4  __attribute__((ext_vector_type(4)));

constexpr float NORM = 0.0625f; // 1/sqrt(256), applied AFTER softmax (faithful)

__device__ __forceinline__ unsigned short f2bf(float f) {
    union { float f; unsigned int u; } v; v.f = f;
    unsigned int r = v.u + 0x7fffu + ((v.u >> 16) & 1u); // RNE
    return (unsigned short)(r >> 16);
}
__device__ __forceinline__ float bf2f(unsigned short s) {
    union { unsigned int u; float f; } v; v.u = ((unsigned int)s) << 16;
    return v.f;
}

// ---------------- bf16 MFMA GEMM: C = act(A @ W^T + bias) -------------------
template<int ACT>
__global__ __launch_bounds__(256)
void gemm_mfma(const float* __restrict__ A, const unsigned short* __restrict__ W,
               const float* __restrict__ bias, float* __restrict__ C,
               int M, int N, int K)
{
    __shared__ short sA[64][72];
    __shared__ short sW[64][72];
    const int tid  = threadIdx.x;
    const int wave = tid >> 6, lane = tid & 63;
    const int quad = lane >> 4, l15 = lane & 15;
    const int m0 = blockIdx.y * 64, n0 = blockIdx.x * 64;
    const int mw = (wave & 1) * 32, nw = (wave >> 1) * 32;
    const int srow = tid >> 2, sseg = tid & 3;

    floatx4 P[2][2];
    #pragma unroll
    for (int f = 0; f < 2; f++)
        #pragma unroll
        for (int g = 0; g < 2; g++)
            P[f][g] = (floatx4){0.f, 0.f, 0.f, 0.f};

    for (int k0 = 0; k0 < K; k0 += 64) {
        const float* ap = A + (size_t)(m0 + srow) * K + k0 + sseg * 16;
        float4 a0 = *(const float4*)(ap);
        float4 a1 = *(const float4*)(ap + 4);
        float4 a2 = *(const float4*)(ap + 8);
        float4 a3 = *(const float4*)(ap + 12);
        union { unsigned short s[8]; short8 v; } p0, p1;
        p0.s[0] = f2bf(a0.x); p0.s[1] = f2bf(a0.y); p0.s[2] = f2bf(a0.z); p0.s[3] = f2bf(a0.w);
        p0.s[4] = f2bf(a1.x); p0.s[5] = f2bf(a1.y); p0.s[6] = f2bf(a1.z); p0.s[7] = f2bf(a1.w);
        p1.s[0] = f2bf(a2.x); p1.s[1] = f2bf(a2.y); p1.s[2] = f2bf(a2.z); p1.s[3] = f2bf(a2.w);
        p1.s[4] = f2bf(a3.x); p1.s[5] = f2bf(a3.y); p1.s[6] = f2bf(a3.z); p1.s[7] = f2bf(a3.w);
        *(short8*)&sA[srow][sseg * 16]     = p0.v;
        *(short8*)&sA[srow][sseg * 16 + 8] = p1.v;
        const unsigned short* wp = W + (size_t)(n0 + srow) * K + k0 + sseg * 16;
        *(short8*)&sW[srow][sseg * 16]     = *(const short8*)wp;
        *(short8*)&sW[srow][sseg * 16 + 8] = *(const short8*)(wp + 8);
        __syncthreads();
        #pragma unroll
        for (int kh = 0; kh < 2; kh++) {
            short8 af[2], wf[2];
            af[0] = *(short8*)&sA[mw + l15][kh * 32 + quad * 8];
            af[1] = *(short8*)&sA[mw + 16 + l15][kh * 32 + quad * 8];
            wf[0] = *(short8*)&sW[nw + l15][kh * 32 + quad * 8];
            wf[1] = *(short8*)&sW[nw + 16 + l15][kh * 32 + quad * 8];
            #pragma unroll
            for (int f = 0; f < 2; f++)
                #pragma unroll
                for (int g = 0; g < 2; g++)
                    P[f][g] = __builtin_amdgcn_mfma_f32_16x16x32_bf16(af[f], wf[g], P[f][g], 0, 0, 0);
        }
        __syncthreads();
    }
    #pragma unroll
    for (int f = 0; f < 2; f++)
        #pragma unroll
        for (int g = 0; g < 2; g++)
            #pragma unroll
            for (int r = 0; r < 4; r++) {
                int m = m0 + mw + 16 * f + quad * 4 + r;
                int n = n0 + nw + 16 * g + l15;
                float v = P[f][g][r] + bias[n];
                if (ACT) v = fmaxf(v, 0.f);
                C[(size_t)m * N + n] = v;
            }
}

// ---------------- fp32 vector GEMM (tiny classifier layers) -----------------
template<int ACT>
__global__ __launch_bounds__(256)
void gemm_bt(const float* __restrict__ A, const float* __restrict__ W,
             const float* __restrict__ bias, float* __restrict__ C,
             int M, int N, int K)
{
    __shared__ __align__(16) float sA[32][68];
    __shared__ __align__(16) float sB[32][68];
    const int tid = threadIdx.x;
    const int m0 = blockIdx.y * 64;
    const int n0 = blockIdx.x * 64;
    const int tx = tid & 15;
    const int ty = tid >> 4;
    const int kk = tid & 31;
    const int rr = tid >> 5;
    float acc[4][4] = {};
    for (int k0 = 0; k0 < K; k0 += 32) {
        #pragma unroll
        for (int p = 0; p < 8; p++) {
            int mm = rr + p * 8;
            int m  = m0 + mm;
            int k  = k0 + kk;
            sA[kk][mm] = (m < M && k < K) ? A[(size_t)m * K + k] : 0.f;
        }
        #pragma unroll
        for (int p = 0; p < 8; p++) {
            int nn = rr + p * 8;
            int n  = n0 + nn;
            int k  = k0 + kk;
            sB[kk][nn] = (n < N && k < K) ? W[(size_t)n * K + k] : 0.f;
        }
        __syncthreads();
        #pragma unroll
        for (int q = 0; q < 32; q++) {
            float av[4], bv[4];
            #pragma unroll
            for (int i = 0; i < 4; i++) av[i] = sA[q][ty * 4 + i];
            #pragma unroll
            for (int j = 0; j < 4; j++) bv[j] = sB[q][tx * 4 + j];
            #pragma unroll
            for (int i = 0; i < 4; i++)
                #pragma unroll
                for (int j = 0; j < 4; j++)
                    acc[i][j] += av[i] * bv[j];
        }
        __syncthreads();
    }
    #pragma unroll
    for (int i = 0; i < 4; i++) {
        int m = m0 + ty * 4 + i;
        if (m >= M) continue;
        #pragma unroll
        for (int j = 0; j < 4; j++) {
            int n = n0 + tx * 4 + j;
            if (n >= N) continue;
            float v = acc[i][j];
            if (bias) v += bias[n];
            if (ACT) v = fmaxf(v, 0.f);
            C[(size_t)m * N + n] = v;
        }
    }
}

// ---------------- fp32 -> bf16 bulk convert ---------------------------------
__global__ __launch_bounds__(256)
void conv_w(const float* __restrict__ src, unsigned short* __restrict__ dst, int n)
{
    int i = (blockIdx.x * 256 + threadIdx.x) * 8;
    if (i + 7 < n) {
        float4 a = *(const float4*)(src + i);
        float4 b = *(const float4*)(src + i + 4);
        union { unsigned short s[8]; uint4 v; } o;
        o.s[0] = f2bf(a.x); o.s[1] = f2bf(a.y); o.s[2] = f2bf(a.z); o.s[3] = f2bf(a.w);
        o.s[4] = f2bf(b.x); o.s[5] = f2bf(b.y); o.s[6] = f2bf(b.z); o.s[7] = f2bf(b.w);
        *(uint4*)(dst + i) = o.v;
    }
}

// K-concat pack: Wcva[o][0:256]=W4[o], [256:512]=W5[o]; same for Wcav from W6,W7
__global__ __launch_bounds__(256)
void pack_kcat(const float* __restrict__ mW, unsigned short* __restrict__ Wcva,
               unsigned short* __restrict__ Wcav)
{
    int i = blockIdx.x * 256 + threadIdx.x; // 65536
    int row = i >> 8, col = i & 255;
    Wcva[row * 512 + col]       = f2bf(mW[4 * 65536 + i]);
    Wcva[row * 512 + 256 + col] = f2bf(mW[5 * 65536 + i]);
    Wcav[row * 512 + col]       = f2bf(mW[6 * 65536 + i]);
    Wcav[row * 512 + 256 + col] = f2bf(mW[7 * 65536 + i]);
}

__global__ __launch_bounds__(256)
void pack_bias(const float* __restrict__ mb, float* __restrict__ bqkv,
               float* __restrict__ bqka, float* __restrict__ bcva,
               float* __restrict__ bcav)
{
    int i = blockIdx.x * 256 + threadIdx.x; // 512
    int c = i & 255;
    bqkv[i] = mb[(i < 256 ? 0 : 512) + c];
    bqka[i] = mb[(i < 256 ? 256 : 768) + c];
    if (i < 256) {
        bcva[i] = mb[4 * 256 + i] + mb[5 * 256 + i];
        bcav[i] = mb[6 * 256 + i] + mb[7 * 256 + i];
    }
}

// ---------------- bilinear: column-per-block --------------------------------
// grid (o=256, mh=2), 256 thr (4 waves). Wave w owns i-range [w*64, w*64+64).
// W_o held as 32 A-frags in VGPRs (loaded once, fp32->bf16 in-register).
// Per m-step (64 rows): cav tile -> LDS (B-operand), 128 MFMA/wave,
// reduction over i in-lane + shfl_xor(16,32) + cross-wave LDS sum.
__global__ __launch_bounds__(256)
void bilinear_col(const unsigned short* __restrict__ cav, // [3072][256] bf16
                  const unsigned short* __restrict__ cva, // [3072][256] bf16
                  const float* __restrict__ Wf,           // [256][256][256] f32
                  float* __restrict__ outT)               // [256][3072] f32
{
    __shared__ short sA[64][264];
    __shared__ float sRed[4][64];
    const int tid  = threadIdx.x;
    const int wave = tid >> 6, lane = tid & 63;
    const int quad = lane >> 4, l15 = lane & 15;
    const int o     = blockIdx.x;
    const int mbase = blockIdx.y * 1536;
    const int i0    = wave * 64;

    // ---- load W_o fragments once: A-frag(f,s): row i = i0+16f+l15, k-chunk
    short8 Wr[4][8];
    {
        const float* wo = Wf + (size_t)o * 65536;
        #pragma unroll
        for (int f = 0; f < 4; f++) {
            const float* wrow = wo + (size_t)(i0 + 16 * f + l15) * 256 + quad * 8;
            #pragma unroll
            for (int s = 0; s < 8; s++) {
                float4 lo = *(const float4*)(wrow + s * 32);
                float4 hi = *(const float4*)(wrow + s * 32 + 4);
                union { unsigned short u[8]; short8 v; } p;
                p.u[0] = f2bf(lo.x); p.u[1] = f2bf(lo.y); p.u[2] = f2bf(lo.z); p.u[3] = f2bf(lo.w);
                p.u[4] = f2bf(hi.x); p.u[5] = f2bf(hi.y); p.u[6] = f2bf(hi.z); p.u[7] = f2bf(hi.w);
                Wr[f][s] = p.v;
            }
        }
    }

    const int srow = tid >> 2, sseg = tid & 3;
    for (int ms = 0; ms < 24; ms++) {
        const int m0 = mbase + ms * 64;
        // stage cav tile [64][256] bf16 (sync at top protects prev readers)
        __syncthreads();
        {
            const unsigned short* src = cav + (size_t)(m0 + srow) * 256 + sseg * 64;
            #pragma unroll
            for (int u = 0; u < 8; u++)
                *(short8*)&sA[srow][sseg * 64 + u * 8] = *(const short8*)(src + u * 8);
        }
        __syncthreads();

        // P2[f][g] : i-tile f (rows), m-tile g (cols); D[i,m] = sum_j W[i,j]cav[m,j]
        floatx4 P2[4][4];
        #pragma unroll
        for (int f = 0; f < 4; f++)
            #pragma unroll
            for (int g = 0; g < 4; g++)
                P2[f][g] = (floatx4){0.f, 0.f, 0.f, 0.f};

        #pragma unroll
        for (int s = 0; s < 8; s++) {
            short8 bg[4];
            #pragma unroll
            for (int g = 0; g < 4; g++)
                bg[g] = *(const short8*)&sA[16 * g + l15][s * 32 + quad * 8];
            #pragma unroll
            for (int f = 0; f < 4; f++)
                #pragma unroll
                for (int g = 0; g < 4; g++)
                    P2[f][g] = __builtin_amdgcn_mfma_f32_16x16x32_bf16(Wr[f][s], bg[g], P2[f][g], 0, 0, 0);
        }

        // T[g] = sum over this wave's i of cva[m,i]*P2[i,m]; m = m0+16g+l15
        float T[4] = {0.f, 0.f, 0.f, 0.f};
        #pragma unroll
        for (int g = 0; g < 4; g++) {
            #pragma unroll
            for (int f = 0; f < 4; f++) {
                uint2 raw = *(const uint2*)(cva + (size_t)(m0 + 16 * g + l15) * 256
                                                 + i0 + 16 * f + 4 * quad);
                float c0 = bf2f((unsigned short)(raw.x & 0xffff));
                float c1 = bf2f((unsigned short)(raw.x >> 16));
                float c2 = bf2f((unsigned short)(raw.y & 0xffff));
                float c3 = bf2f((unsigned short)(raw.y >> 16));
                T[g] += c0 * P2[f][g][0] + c1 * P2[f][g][1]
                      + c2 * P2[f][g][2] + c3 * P2[f][g][3];
            }
        }
        #pragma unroll
        for (int g = 0; g < 4; g++) {
            T[g] += __shfl_xor(T[g], 16);
            T[g] += __shfl_xor(T[g], 32);
        }
        if (quad == 0) {
            #pragma unroll
            for (int g = 0; g < 4; g++)
                sRed[wave][16 * g + l15] = T[g];
        }
        __syncthreads();
        if (tid < 64)
            outT[(size_t)o * 3072 + m0 + tid] =
                sRed[0][tid] + sRed[1][tid] + sRed[2][tid] + sRed[3][tid];
    }
}

// ---------------- attention (packed q/k [3072][512], packed alpha out) ------
__global__ __launch_bounds__(256)
void attn_packed(const float* __restrict__ qkv, const float* __restrict__ qka,
                 const float* __restrict__ xv, const float* __restrict__ xa,
                 float* __restrict__ al_v, float* __restrict__ al_a)
{
    const int b    = blockIdx.x;
    const int tid  = threadIdx.x;
    const int wave = tid >> 6;
    const int lane = tid & 63;
    __shared__ float att[4][3][3];
    const size_t b512 = (size_t)b * 1536;
    const size_t b768 = (size_t)b * 768;
    const float* Qs[4] = {qkv, qkv, qka, qka};
    const float* Ks[4] = {qka + 256, qkv + 256, qkv + 256, qka + 256};
    const float* Xs[4] = {xa, xv, xv, xa};
    float*       Os[4] = {al_v, al_v + 256, al_a, al_a + 256};
    const float* q = Qs[wave] + b512;
    const float* k = Ks[wave] + b512;
    float part[9] = {};
    for (int d = lane; d < 256; d += 64) {
        float q0 = q[d], q1 = q[512 + d], q2 = q[1024 + d];
        float k0 = k[d], k1 = k[512 + d], k2 = k[1024 + d];
        part[0] += q0 * k0; part[1] += q0 * k1; part[2] += q0 * k2;
        part[3] += q1 * k0; part[4] += q1 * k1; part[5] += q1 * k2;
        part[6] += q2 * k0; part[7] += q2 * k1; part[8] += q2 * k2;
    }
    #pragma unroll
    for (int off = 32; off > 0; off >>= 1)
        #pragma unroll
        for (int i = 0; i < 9; i++) part[i] += __shfl_down(part[i], off);
    if (lane == 0) {
        #pragma unroll
        for (int s = 0; s < 3; s++) {
            float a0 = part[s * 3], a1 = part[s * 3 + 1], a2 = part[s * 3 + 2];
            float mx = fmaxf(a0, fmaxf(a1, a2));
            float e0 = expf(a0 - mx), e1 = expf(a1 - mx), e2 = expf(a2 - mx);
            float inv = NORM / (e0 + e1 + e2);
            att[wave][s][0] = e0 * inv;
            att[wave][s][1] = e1 * inv;
            att[wave][s][2] = e2 * inv;
        }
    }
    __syncthreads();
    const int d = tid;
    #pragma unroll
    for (int w = 0; w < 4; w++) {
        const float* x = Xs[w] + b768;
        float x0 = x[d], x1 = x[256 + d], x2 = x[512 + d];
        float* o = Os[w] + b512;
        #pragma unroll
        for (int s = 0; s < 3; s++)
            o[s * 512 + d] = att[w][s][0] * x0 + att[w][s][1] * x1 + att[w][s][2] * x2;
    }
}

// ---------------- elementwise ----------------------------------------------
// c = sigmoid(Cg * alpha), alpha = packed[.,256:512] -> bf16 [3072][256]
__global__ void ew_c(const float* __restrict__ Cg, const float* __restrict__ al,
                     unsigned short* __restrict__ outp, int n)
{
    int i = blockIdx.x * 256 + threadIdx.x;
    if (i < n) {
        int row = i >> 8, col = i & 255;
        float a = al[(size_t)row * 512 + 256 + col];
        float v = Cg[i] * a;
        outp[i] = f2bf(1.f / (1.f + expf(-v)));
    }
}

__global__ void ew_mix(const float* __restrict__ logitsT, const float* __restrict__ xv,
                       const float* __restrict__ xa, const float* __restrict__ bv,
                       const float* __restrict__ ba, const float* __restrict__ tc,
                       float* __restrict__ outv, float* __restrict__ outa, int n)
{
    int i = blockIdx.x * 256 + threadIdx.x;
    if (i < n) {
        int m = i >> 8, o = i & 255;
        float j = 1.f / (1.f + expf(-logitsT[(size_t)o * 3072 + m]));
        float M = tc[0] * j * xv[i] + (1.f - j) * xa[i];
        outv[i] = M * bv[i];
        outa[i] = M * ba[i];
    }
}

// ---------------------------------------------------------------------------
extern "C" void kernel_launch(void* const* d_in, const int* in_sizes, int n_in,
                              void* d_out, int out_size, void* d_ws, size_t ws_size,
                              hipStream_t stream)
{
    const float* img    = (const float*)d_in[0];
    const float* audio  = (const float*)d_in[1];
    const float* vis_W  = (const float*)d_in[2];
    const float* vis_b  = (const float*)d_in[3];
    const float* aud_W  = (const float*)d_in[4];
    const float* aud_b  = (const float*)d_in[5];
    const float* msv_W  = (const float*)d_in[6];
    const float* msv_b  = (const float*)d_in[7];
    const float* msa_W  = (const float*)d_in[8];
    const float* msa_b  = (const float*)d_in[9];
    const float* mmfa_W = (const float*)d_in[10];
    const float* mmfa_b = (const float*)d_in[11];
    const float* bil_W  = (const float*)d_in[12];
    const float* t_c    = (const float*)d_in[13];
    const float* out_W1 = (const float*)d_in[14];
    const float* out_b1 = (const float*)d_in[15];
    const float* out_W2 = (const float*)d_in[16];
    const float* out_b2 = (const float*)d_in[17];
    const float* clsv_W1 = (const float*)d_in[18];
    const float* clsv_W2 = (const float*)d_in[19];
    const float* clsa_W1 = (const float*)d_in[20];
    const float* clsa_W2 = (const float*)d_in[21];
    float* out = (float*)d_out;
    float* ws  = (float*)d_ws;

    constexpr size_t SD = 3072 * 256; // 786432
    // ---- scratch region S
    float* S = ws;
    unsigned short* visbf = (unsigned short*)(S + 2097152);
    unsigned short* audbf = (unsigned short*)(S + 4194304);
    unsigned short* msvbf = (unsigned short*)(S + 4718592);
    unsigned short* msabf = (unsigned short*)(S + 5111808);
    float* vis  = S;
    float* aud  = S + 1048576;
    float* qkv  = S;
    float* qka  = S + 1572864;
    float* al_v = S + 3145728;
    float* al_a = S + 4718592;
    float* Cg   = S + 6291456;
    float* ovb  = S;                  // end-phase
    float* oab  = S + SD;
    float* hv   = S + 2 * SD;
    float* hc   = S + 2 * SD + 524288;
    unsigned short* W1bf = (unsigned short*)(S + 2 * SD + 557056);
    unsigned short* W2bf = W1bf + 393216;
    // ---- persistent region
    float* P = ws + 8388608;
    float* v_ms    = P;
    float* a_ms    = P + SD;
    float* x_v2    = P + 2 * SD;
    float* x_a2    = P + 3 * SD;
    float* logitsT = P + 4 * SD;                                  // [256][3072]
    unsigned short* c_va = (unsigned short*)(P + 5 * SD);         // [3072][256] bf16
    unsigned short* c_av = (unsigned short*)(P + 5 * SD + SD / 2);
    unsigned short* Wqkv = (unsigned short*)(P + 6 * SD);
    unsigned short* Wqka = Wqkv + 131072;
    unsigned short* Wcva = Wqka + 131072;
    unsigned short* Wcav = Wcva + 131072;
    float* bqkv = P + 6 * SD + 262144;
    float* bqka = bqkv + 512;
    float* bcva = bqka + 512;
    float* bcav = bcva + 256;

    auto gmf = [&](const float* A, const unsigned short* W, const float* bias,
                   float* C, int M, int N, int K, int act) {
        dim3 g(N / 64, M / 64);
        if (act) gemm_mfma<1><<<g, 256, 0, stream>>>(A, W, bias, C, M, N, K);
        else     gemm_mfma<0><<<g, 256, 0, stream>>>(A, W, bias, C, M, N, K);
    };
    auto gbt = [&](const float* A, const float* W, const float* bias, float* C,
                   int M, int N, int K, int act) {
        dim3 g((N + 63) / 64, (M + 63) / 64);
        if (act) gemm_bt<1><<<g, 256, 0, stream>>>(A, W, bias, C, M, N, K);
        else     gemm_bt<0><<<g, 256, 0, stream>>>(A, W, bias, C, M, N, K);
    };

    // ---- weight packing (once per launch)
    conv_w<<<2048, 256, 0, stream>>>(vis_W, visbf, 4194304);
    conv_w<<<512,  256, 0, stream>>>(aud_W, audbf, 1048576);
    conv_w<<<384,  256, 0, stream>>>(msv_W, msvbf, 786432);
    conv_w<<<384,  256, 0, stream>>>(msa_W, msabf, 786432);
    conv_w<<<32, 256, 0, stream>>>(mmfa_W + 0 * 65536, Wqkv, 65536);
    conv_w<<<32, 256, 0, stream>>>(mmfa_W + 2 * 65536, Wqkv + 65536, 65536);
    conv_w<<<32, 256, 0, stream>>>(mmfa_W + 1 * 65536, Wqka, 65536);
    conv_w<<<32, 256, 0, stream>>>(mmfa_W + 3 * 65536, Wqka + 65536, 65536);
    pack_kcat<<<256, 256, 0, stream>>>(mmfa_W, Wcva, Wcav);
    pack_bias<<<2, 256, 0, stream>>>(mmfa_b, bqkv, bqka, bcva, bcav);

    // ---- encoders + multiscale
    gmf(img,   visbf, vis_b, vis, 1024, 1024, 4096, 1);
    gmf(audio, audbf, aud_b, aud, 1024, 1024, 1024, 1);
    gmf(vis, msvbf, msv_b, v_ms, 1024, 768, 1024, 1);
    gmf(aud, msabf, msa_b, a_ms, 1024, 768, 1024, 1);

    const int EW_N = (int)SD;
    const int EW_G = (EW_N + 255) / 256;

    auto mmfa = [&](const float* xv, const float* xa, float* outv, float* outa) {
        gmf(xv, Wqkv, bqkv, qkv, 3072, 512, 256, 0);
        gmf(xa, Wqka, bqka, qka, 3072, 512, 256, 0);
        attn_packed<<<1024, 256, 0, stream>>>(qkv, qka, xv, xa, al_v, al_a);
        gmf(al_v, Wcva, bcva, Cg, 3072, 256, 512, 0);
        ew_c<<<EW_G, 256, 0, stream>>>(Cg, al_v, c_va, EW_N);
        gmf(al_a, Wcav, bcav, Cg, 3072, 256, 512, 0);
        ew_c<<<EW_G, 256, 0, stream>>>(Cg, al_a, c_av, EW_N);
        bilinear_col<<<dim3(256, 2), 256, 0, stream>>>(c_av, c_va, bil_W, logitsT);
        ew_mix<<<EW_G, 256, 0, stream>>>(logitsT, xv, xa, v_ms, a_ms, t_c,
                                         outv, outa, EW_N);
    };

    mmfa(v_ms, a_ms, x_v2, x_a2);   // M1 stage
    mmfa(x_v2, x_a2, ovb, oab);     // M2 stage

    float* fv = out;
    float* fa = out + 1024 * 128;
    float* pv = out + 2 * 1024 * 128;
    float* pa = pv + 1024 * 10;

    conv_w<<<192, 256, 0, stream>>>(out_W1, W1bf, 393216);
    conv_w<<<32,  256, 0, stream>>>(out_W2, W2bf, 65536);
    gmf(ovb, W1bf, out_b1, hv, 1024, 512, 768, 1);
    gmf(hv,  W2bf, out_b2, fv, 1024, 128, 512, 0);
    gmf(oab, W1bf, out_b1, hv, 1024, 512, 768, 1);
    gmf(hv,  W2bf, out_b2, fa, 1024, 128, 512, 0);

    gbt(fv, clsv_W1, nullptr, hc, 1024, 32, 128, 1);
    gbt(hc, clsv_W2, nullptr, pv, 1024, 10, 32, 0);
    gbt(fa, clsa_W1, nullptr, hc, 1024, 32, 128, 1);
    gbt(hc, clsa_W2, nullptr, pa, 1024, 10, 32, 0);

    (void)in_sizes; (void)n_in; (void)out_size; (void)ws_size;
}

// Round 5
// 866.406 us; speedup vs baseline: 7.0552x; 1.1483x over previous
//
#include <hip/hip_runtime.h>
#include <math.h>

// ---------------------------------------------------------------------------
// CrossModal_NN — round 5: occupancy-focused bilinear + ew_c fusion.
// bilinear_col: 512 thr / 8 waves, wave owns 32-i slice (Wr[2][8]=64 VGPR),
// __launch_bounds__(512,4) -> <=128 VGPR -> 2 blocks/CU = 16 waves/CU.
// gemm_sigm: Cg GEMM with fused sigmoid(G*alpha)->bf16 epilogue (kills ew_c).
// ---------------------------------------------------------------------------

typedef short short8   __attribute__((ext_vector_type(8)));
typedef float floatx4  __attribute__((ext_vector_type(4)));

constexpr float NORM = 0.0625f; // 1/sqrt(256), applied AFTER softmax (faithful)

__device__ __forceinline__ unsigned short f2bf(float f) {
    union { float f; unsigned int u; } v; v.f = f;
    unsigned int r = v.u + 0x7fffu + ((v.u >> 16) & 1u); // RNE
    return (unsigned short)(r >> 16);
}
__device__ __forceinline__ float bf2f(unsigned short s) {
    union { unsigned int u; float f; } v; v.u = ((unsigned int)s) << 16;
    return v.f;
}

// ---------------- bf16 MFMA GEMM: C = act(A @ W^T + bias) -------------------
template<int ACT>
__global__ __launch_bounds__(256)
void gemm_mfma(const float* __restrict__ A, const unsigned short* __restrict__ W,
               const float* __restrict__ bias, float* __restrict__ C,
               int M, int N, int K)
{
    __shared__ short sA[64][72];
    __shared__ short sW[64][72];
    const int tid  = threadIdx.x;
    const int wave = tid >> 6, lane = tid & 63;
    const int quad = lane >> 4, l15 = lane & 15;
    const int m0 = blockIdx.y * 64, n0 = blockIdx.x * 64;
    const int mw = (wave & 1) * 32, nw = (wave >> 1) * 32;
    const int srow = tid >> 2, sseg = tid & 3;

    floatx4 P[2][2];
    #pragma unroll
    for (int f = 0; f < 2; f++)
        #pragma unroll
        for (int g = 0; g < 2; g++)
            P[f][g] = (floatx4){0.f, 0.f, 0.f, 0.f};

    for (int k0 = 0; k0 < K; k0 += 64) {
        const float* ap = A + (size_t)(m0 + srow) * K + k0 + sseg * 16;
        float4 a0 = *(const float4*)(ap);
        float4 a1 = *(const float4*)(ap + 4);
        float4 a2 = *(const float4*)(ap + 8);
        float4 a3 = *(const float4*)(ap + 12);
        union { unsigned short s[8]; short8 v; } p0, p1;
        p0.s[0] = f2bf(a0.x); p0.s[1] = f2bf(a0.y); p0.s[2] = f2bf(a0.z); p0.s[3] = f2bf(a0.w);
        p0.s[4] = f2bf(a1.x); p0.s[5] = f2bf(a1.y); p0.s[6] = f2bf(a1.z); p0.s[7] = f2bf(a1.w);
        p1.s[0] = f2bf(a2.x); p1.s[1] = f2bf(a2.y); p1.s[2] = f2bf(a2.z); p1.s[3] = f2bf(a2.w);
        p1.s[4] = f2bf(a3.x); p1.s[5] = f2bf(a3.y); p1.s[6] = f2bf(a3.z); p1.s[7] = f2bf(a3.w);
        *(short8*)&sA[srow][sseg * 16]     = p0.v;
        *(short8*)&sA[srow][sseg * 16 + 8] = p1.v;
        const unsigned short* wp = W + (size_t)(n0 + srow) * K + k0 + sseg * 16;
        *(short8*)&sW[srow][sseg * 16]     = *(const short8*)wp;
        *(short8*)&sW[srow][sseg * 16 + 8] = *(const short8*)(wp + 8);
        __syncthreads();
        #pragma unroll
        for (int kh = 0; kh < 2; kh++) {
            short8 af[2], wf[2];
            af[0] = *(short8*)&sA[mw + l15][kh * 32 + quad * 8];
            af[1] = *(short8*)&sA[mw + 16 + l15][kh * 32 + quad * 8];
            wf[0] = *(short8*)&sW[nw + l15][kh * 32 + quad * 8];
            wf[1] = *(short8*)&sW[nw + 16 + l15][kh * 32 + quad * 8];
            #pragma unroll
            for (int f = 0; f < 2; f++)
                #pragma unroll
                for (int g = 0; g < 2; g++)
                    P[f][g] = __builtin_amdgcn_mfma_f32_16x16x32_bf16(af[f], wf[g], P[f][g], 0, 0, 0);
        }
        __syncthreads();
    }
    #pragma unroll
    for (int f = 0; f < 2; f++)
        #pragma unroll
        for (int g = 0; g < 2; g++)
            #pragma unroll
            for (int r = 0; r < 4; r++) {
                int m = m0 + mw + 16 * f + quad * 4 + r;
                int n = n0 + nw + 16 * g + l15;
                float v = P[f][g][r] + bias[n];
                if (ACT) v = fmaxf(v, 0.f);
                C[(size_t)m * N + n] = v;
            }
}

// ---- same GEMM with fused sigmoid(G*alpha) -> bf16 epilogue (replaces ew_c)
__global__ __launch_bounds__(256)
void gemm_sigm(const float* __restrict__ A, const unsigned short* __restrict__ W,
               const float* __restrict__ bias, const float* __restrict__ al,
               unsigned short* __restrict__ Cbf, int M, int N, int K)
{
    __shared__ short sA[64][72];
    __shared__ short sW[64][72];
    const int tid  = threadIdx.x;
    const int wave = tid >> 6, lane = tid & 63;
    const int quad = lane >> 4, l15 = lane & 15;
    const int m0 = blockIdx.y * 64, n0 = blockIdx.x * 64;
    const int mw = (wave & 1) * 32, nw = (wave >> 1) * 32;
    const int srow = tid >> 2, sseg = tid & 3;

    floatx4 P[2][2];
    #pragma unroll
    for (int f = 0; f < 2; f++)
        #pragma unroll
        for (int g = 0; g < 2; g++)
            P[f][g] = (floatx4){0.f, 0.f, 0.f, 0.f};

    for (int k0 = 0; k0 < K; k0 += 64) {
        const float* ap = A + (size_t)(m0 + srow) * K + k0 + sseg * 16;
        float4 a0 = *(const float4*)(ap);
        float4 a1 = *(const float4*)(ap + 4);
        float4 a2 = *(const float4*)(ap + 8);
        float4 a3 = *(const float4*)(ap + 12);
        union { unsigned short s[8]; short8 v; } p0, p1;
        p0.s[0] = f2bf(a0.x); p0.s[1] = f2bf(a0.y); p0.s[2] = f2bf(a0.z); p0.s[3] = f2bf(a0.w);
        p0.s[4] = f2bf(a1.x); p0.s[5] = f2bf(a1.y); p0.s[6] = f2bf(a1.z); p0.s[7] = f2bf(a1.w);
        p1.s[0] = f2bf(a2.x); p1.s[1] = f2bf(a2.y); p1.s[2] = f2bf(a2.z); p1.s[3] = f2bf(a2.w);
        p1.s[4] = f2bf(a3.x); p1.s[5] = f2bf(a3.y); p1.s[6] = f2bf(a3.z); p1.s[7] = f2bf(a3.w);
        *(short8*)&sA[srow][sseg * 16]     = p0.v;
        *(short8*)&sA[srow][sseg * 16 + 8] = p1.v;
        const unsigned short* wp = W + (size_t)(n0 + srow) * K + k0 + sseg * 16;
        *(short8*)&sW[srow][sseg * 16]     = *(const short8*)wp;
        *(short8*)&sW[srow][sseg * 16 + 8] = *(const short8*)(wp + 8);
        __syncthreads();
        #pragma unroll
        for (int kh = 0; kh < 2; kh++) {
            short8 af[2], wf[2];
            af[0] = *(short8*)&sA[mw + l15][kh * 32 + quad * 8];
            af[1] = *(short8*)&sA[mw + 16 + l15][kh * 32 + quad * 8];
            wf[0] = *(short8*)&sW[nw + l15][kh * 32 + quad * 8];
            wf[1] = *(short8*)&sW[nw + 16 + l15][kh * 32 + quad * 8];
            #pragma unroll
            for (int f = 0; f < 2; f++)
                #pragma unroll
                for (int g = 0; g < 2; g++)
                    P[f][g] = __builtin_amdgcn_mfma_f32_16x16x32_bf16(af[f], wf[g], P[f][g], 0, 0, 0);
        }
        __syncthreads();
    }
    #pragma unroll
    for (int f = 0; f < 2; f++)
        #pragma unroll
        for (int g = 0; g < 2; g++)
            #pragma unroll
            for (int r = 0; r < 4; r++) {
                int m = m0 + mw + 16 * f + quad * 4 + r;
                int n = n0 + nw + 16 * g + l15;
                float v = P[f][g][r] + bias[n];
                float a = al[(size_t)m * 512 + 256 + n];
                Cbf[(size_t)m * N + n] = f2bf(1.f / (1.f + expf(-v * a)));
            }
}

// ---------------- fp32 vector GEMM (tiny classifier layers) -----------------
template<int ACT>
__global__ __launch_bounds__(256)
void gemm_bt(const float* __restrict__ A, const float* __restrict__ W,
             const float* __restrict__ bias, float* __restrict__ C,
             int M, int N, int K)
{
    __shared__ __align__(16) float sA[32][68];
    __shared__ __align__(16) float sB[32][68];
    const int tid = threadIdx.x;
    const int m0 = blockIdx.y * 64;
    const int n0 = blockIdx.x * 64;
    const int tx = tid & 15;
    const int ty = tid >> 4;
    const int kk = tid & 31;
    const int rr = tid >> 5;
    float acc[4][4] = {};
    for (int k0 = 0; k0 < K; k0 += 32) {
        #pragma unroll
        for (int p = 0; p < 8; p++) {
            int mm = rr + p * 8;
            int m  = m0 + mm;
            int k  = k0 + kk;
            sA[kk][mm] = (m < M && k < K) ? A[(size_t)m * K + k] : 0.f;
        }
        #pragma unroll
        for (int p = 0; p < 8; p++) {
            int nn = rr + p * 8;
            int n  = n0 + nn;
            int k  = k0 + kk;
            sB[kk][nn] = (n < N && k < K) ? W[(size_t)n * K + k] : 0.f;
        }
        __syncthreads();
        #pragma unroll
        for (int q = 0; q < 32; q++) {
            float av[4], bv[4];
            #pragma unroll
            for (int i = 0; i < 4; i++) av[i] = sA[q][ty * 4 + i];
            #pragma unroll
            for (int j = 0; j < 4; j++) bv[j] = sB[q][tx * 4 + j];
            #pragma unroll
            for (int i = 0; i < 4; i++)
                #pragma unroll
                for (int j = 0; j < 4; j++)
                    acc[i][j] += av[i] * bv[j];
        }
        __syncthreads();
    }
    #pragma unroll
    for (int i = 0; i < 4; i++) {
        int m = m0 + ty * 4 + i;
        if (m >= M) continue;
        #pragma unroll
        for (int j = 0; j < 4; j++) {
            int n = n0 + tx * 4 + j;
            if (n >= N) continue;
            float v = acc[i][j];
            if (bias) v += bias[n];
            if (ACT) v = fmaxf(v, 0.f);
            C[(size_t)m * N + n] = v;
        }
    }
}

// ---------------- fp32 -> bf16 bulk convert ---------------------------------
__global__ __launch_bounds__(256)
void conv_w(const float* __restrict__ src, unsigned short* __restrict__ dst, int n)
{
    int i = (blockIdx.x * 256 + threadIdx.x) * 8;
    if (i + 7 < n) {
        float4 a = *(const float4*)(src + i);
        float4 b = *(const float4*)(src + i + 4);
        union { unsigned short s[8]; uint4 v; } o;
        o.s[0] = f2bf(a.x); o.s[1] = f2bf(a.y); o.s[2] = f2bf(a.z); o.s[3] = f2bf(a.w);
        o.s[4] = f2bf(b.x); o.s[5] = f2bf(b.y); o.s[6] = f2bf(b.z); o.s[7] = f2bf(b.w);
        *(uint4*)(dst + i) = o.v;
    }
}

__global__ __launch_bounds__(256)
void pack_kcat(const float* __restrict__ mW, unsigned short* __restrict__ Wcva,
               unsigned short* __restrict__ Wcav)
{
    int i = blockIdx.x * 256 + threadIdx.x; // 65536
    int row = i >> 8, col = i & 255;
    Wcva[row * 512 + col]       = f2bf(mW[4 * 65536 + i]);
    Wcva[row * 512 + 256 + col] = f2bf(mW[5 * 65536 + i]);
    Wcav[row * 512 + col]       = f2bf(mW[6 * 65536 + i]);
    Wcav[row * 512 + 256 + col] = f2bf(mW[7 * 65536 + i]);
}

__global__ __launch_bounds__(256)
void pack_bias(const float* __restrict__ mb, float* __restrict__ bqkv,
               float* __restrict__ bqka, float* __restrict__ bcva,
               float* __restrict__ bcav)
{
    int i = blockIdx.x * 256 + threadIdx.x; // 512
    int c = i & 255;
    bqkv[i] = mb[(i < 256 ? 0 : 512) + c];
    bqka[i] = mb[(i < 256 ? 256 : 768) + c];
    if (i < 256) {
        bcva[i] = mb[4 * 256 + i] + mb[5 * 256 + i];
        bcav[i] = mb[6 * 256 + i] + mb[7 * 256 + i];
    }
}

// ---------------- bilinear: column-per-block, 8 waves -----------------------
// grid (o=256, mh=2), 512 thr. Wave w owns i in [w*32, w*32+32).
// W_o frags in VGPRs (Wr[2][8] = 64 VGPR), cav tile via LDS.
__global__ __launch_bounds__(512, 4)
void bilinear_col(const unsigned short* __restrict__ cav, // [3072][256] bf16
                  const unsigned short* __restrict__ cva, // [3072][256] bf16
                  const float* __restrict__ Wf,           // [256][256][256] f32
                  float* __restrict__ outT)               // [256][3072] f32
{
    __shared__ short sA[64][264];
    __shared__ float sRed[8][64];
    const int tid  = threadIdx.x;
    const int wave = tid >> 6, lane = tid & 63;
    const int quad = lane >> 4, l15 = lane & 15;
    const int o     = blockIdx.x;
    const int mbase = blockIdx.y * 1536;
    const int i0    = wave * 32;

    // ---- load W_o fragments once (fp32 -> bf16 in-register)
    short8 Wr[2][8];
    {
        const float* wo = Wf + (size_t)o * 65536;
        #pragma unroll
        for (int f = 0; f < 2; f++) {
            const float* wrow = wo + (size_t)(i0 + 16 * f + l15) * 256 + quad * 8;
            #pragma unroll
            for (int s = 0; s < 8; s++) {
                float4 lo = *(const float4*)(wrow + s * 32);
                float4 hi = *(const float4*)(wrow + s * 32 + 4);
                union { unsigned short u[8]; short8 v; } p;
                p.u[0] = f2bf(lo.x); p.u[1] = f2bf(lo.y); p.u[2] = f2bf(lo.z); p.u[3] = f2bf(lo.w);
                p.u[4] = f2bf(hi.x); p.u[5] = f2bf(hi.y); p.u[6] = f2bf(hi.z); p.u[7] = f2bf(hi.w);
                Wr[f][s] = p.v;
            }
        }
    }

    const int srow = tid >> 3, sseg = tid & 7;
    for (int ms = 0; ms < 24; ms++) {
        const int m0 = mbase + ms * 64;
        __syncthreads();   // prev-step sA readers done
        {
            const unsigned short* src = cav + (size_t)(m0 + srow) * 256 + sseg * 32;
            #pragma unroll
            for (int u = 0; u < 4; u++)
                *(short8*)&sA[srow][sseg * 32 + u * 8] = *(const short8*)(src + u * 8);
        }
        __syncthreads();

        // issue cva loads early (overlap with MFMA burst)
        uint2 raws[2][4];
        #pragma unroll
        for (int g = 0; g < 4; g++)
            #pragma unroll
            for (int f = 0; f < 2; f++)
                raws[f][g] = *(const uint2*)(cva + (size_t)(m0 + 16 * g + l15) * 256
                                                  + i0 + 16 * f + 4 * quad);

        floatx4 P2[2][4];
        #pragma unroll
        for (int f = 0; f < 2; f++)
            #pragma unroll
            for (int g = 0; g < 4; g++)
                P2[f][g] = (floatx4){0.f, 0.f, 0.f, 0.f};

        #pragma unroll
        for (int s = 0; s < 8; s++) {
            short8 bg[4];
            #pragma unroll
            for (int g = 0; g < 4; g++)
                bg[g] = *(const short8*)&sA[16 * g + l15][s * 32 + quad * 8];
            #pragma unroll
            for (int f = 0; f < 2; f++)
                #pragma unroll
                for (int g = 0; g < 4; g++)
                    P2[f][g] = __builtin_amdgcn_mfma_f32_16x16x32_bf16(Wr[f][s], bg[g], P2[f][g], 0, 0, 0);
        }

        float T[4] = {0.f, 0.f, 0.f, 0.f};
        #pragma unroll
        for (int g = 0; g < 4; g++)
            #pragma unroll
            for (int f = 0; f < 2; f++) {
                uint2 raw = raws[f][g];
                T[g] += bf2f((unsigned short)(raw.x & 0xffff)) * P2[f][g][0]
                      + bf2f((unsigned short)(raw.x >> 16))    * P2[f][g][1]
                      + bf2f((unsigned short)(raw.y & 0xffff)) * P2[f][g][2]
                      + bf2f((unsigned short)(raw.y >> 16))    * P2[f][g][3];
            }
        #pragma unroll
        for (int g = 0; g < 4; g++) {
            T[g] += __shfl_xor(T[g], 16);
            T[g] += __shfl_xor(T[g], 32);
        }
        if (quad == 0) {
            #pragma unroll
            for (int g = 0; g < 4; g++)
                sRed[wave][16 * g + l15] = T[g];
        }
        __syncthreads();
        if (tid < 64) {
            float acc = sRed[0][tid] + sRed[1][tid] + sRed[2][tid] + sRed[3][tid]
                      + sRed[4][tid] + sRed[5][tid] + sRed[6][tid] + sRed[7][tid];
            outT[(size_t)o * 3072 + m0 + tid] = acc;
        }
    }
}

// ---------------- attention (packed q/k [3072][512], packed alpha out) ------
__global__ __launch_bounds__(256)
void attn_packed(const float* __restrict__ qkv, const float* __restrict__ qka,
                 const float* __restrict__ xv, const float* __restrict__ xa,
                 float* __restrict__ al_v, float* __restrict__ al_a)
{
    const int b    = blockIdx.x;
    const int tid  = threadIdx.x;
    const int wave = tid >> 6;
    const int lane = tid & 63;
    __shared__ float att[4][3][3];
    const size_t b512 = (size_t)b * 1536;
    const size_t b768 = (size_t)b * 768;
    const float* Qs[4] = {qkv, qkv, qka, qka};
    const float* Ks[4] = {qka + 256, qkv + 256, qkv + 256, qka + 256};
    const float* Xs[4] = {xa, xv, xv, xa};
    float*       Os[4] = {al_v, al_v + 256, al_a, al_a + 256};
    const float* q = Qs[wave] + b512;
    const float* k = Ks[wave] + b512;
    float part[9] = {};
    for (int d = lane; d < 256; d += 64) {
        float q0 = q[d], q1 = q[512 + d], q2 = q[1024 + d];
        float k0 = k[d], k1 = k[512 + d], k2 = k[1024 + d];
        part[0] += q0 * k0; part[1] += q0 * k1; part[2] += q0 * k2;
        part[3] += q1 * k0; part[4] += q1 * k1; part[5] += q1 * k2;
        part[6] += q2 * k0; part[7] += q2 * k1; part[8] += q2 * k2;
    }
    #pragma unroll
    for (int off = 32; off > 0; off >>= 1)
        #pragma unroll
        for (int i = 0; i < 9; i++) part[i] += __shfl_down(part[i], off);
    if (lane == 0) {
        #pragma unroll
        for (int s = 0; s < 3; s++) {
            float a0 = part[s * 3], a1 = part[s * 3 + 1], a2 = part[s * 3 + 2];
            float mx = fmaxf(a0, fmaxf(a1, a2));
            float e0 = expf(a0 - mx), e1 = expf(a1 - mx), e2 = expf(a2 - mx);
            float inv = NORM / (e0 + e1 + e2);
            att[wave][s][0] = e0 * inv;
            att[wave][s][1] = e1 * inv;
            att[wave][s][2] = e2 * inv;
        }
    }
    __syncthreads();
    const int d = tid;
    #pragma unroll
    for (int w = 0; w < 4; w++) {
        const float* x = Xs[w] + b768;
        float x0 = x[d], x1 = x[256 + d], x2 = x[512 + d];
        float* o = Os[w] + b512;
        #pragma unroll
        for (int s = 0; s < 3; s++)
            o[s * 512 + d] = att[w][s][0] * x0 + att[w][s][1] * x1 + att[w][s][2] * x2;
    }
}

// ---------------- elementwise ----------------------------------------------
__global__ void ew_mix(const float* __restrict__ logitsT, const float* __restrict__ xv,
                       const float* __restrict__ xa, const float* __restrict__ bv,
                       const float* __restrict__ ba, const float* __restrict__ tc,
                       float* __restrict__ outv, float* __restrict__ outa, int n)
{
    int i = blockIdx.x * 256 + threadIdx.x;
    if (i < n) {
        int m = i >> 8, o = i & 255;
        float j = 1.f / (1.f + expf(-logitsT[(size_t)o * 3072 + m]));
        float M = tc[0] * j * xv[i] + (1.f - j) * xa[i];
        outv[i] = M * bv[i];
        outa[i] = M * ba[i];
    }
}

// ---------------------------------------------------------------------------
extern "C" void kernel_launch(void* const* d_in, const int* in_sizes, int n_in,
                              void* d_out, int out_size, void* d_ws, size_t ws_size,
                              hipStream_t stream)
{
    const float* img    = (const float*)d_in[0];
    const float* audio  = (const float*)d_in[1];
    const float* vis_W  = (const float*)d_in[2];
    const float* vis_b  = (const float*)d_in[3];
    const float* aud_W  = (const float*)d_in[4];
    const float* aud_b  = (const float*)d_in[5];
    const float* msv_W  = (const float*)d_in[6];
    const float* msv_b  = (const float*)d_in[7];
    const float* msa_W  = (const float*)d_in[8];
    const float* msa_b  = (const float*)d_in[9];
    const float* mmfa_W = (const float*)d_in[10];
    const float* mmfa_b = (const float*)d_in[11];
    const float* bil_W  = (const float*)d_in[12];
    const float* t_c    = (const float*)d_in[13];
    const float* out_W1 = (const float*)d_in[14];
    const float* out_b1 = (const float*)d_in[15];
    const float* out_W2 = (const float*)d_in[16];
    const float* out_b2 = (const float*)d_in[17];
    const float* clsv_W1 = (const float*)d_in[18];
    const float* clsv_W2 = (const float*)d_in[19];
    const float* clsa_W1 = (const float*)d_in[20];
    const float* clsa_W2 = (const float*)d_in[21];
    float* out = (float*)d_out;
    float* ws  = (float*)d_ws;

    constexpr size_t SD = 3072 * 256; // 786432
    // ---- scratch region S
    float* S = ws;
    unsigned short* visbf = (unsigned short*)(S + 2097152);
    unsigned short* audbf = (unsigned short*)(S + 4194304);
    unsigned short* msvbf = (unsigned short*)(S + 4718592);
    unsigned short* msabf = (unsigned short*)(S + 5111808);
    float* vis  = S;
    float* aud  = S + 1048576;
    float* qkv  = S;
    float* qka  = S + 1572864;
    float* al_v = S + 3145728;
    float* al_a = S + 4718592;
    float* ovb  = S;                  // end-phase
    float* oab  = S + SD;
    float* hv   = S + 2 * SD;
    float* hc   = S + 2 * SD + 524288;
    unsigned short* W1bf = (unsigned short*)(S + 2 * SD + 557056);
    unsigned short* W2bf = W1bf + 393216;
    // ---- persistent region
    float* P = ws + 8388608;
    float* v_ms    = P;
    float* a_ms    = P + SD;
    float* x_v2    = P + 2 * SD;
    float* x_a2    = P + 3 * SD;
    float* logitsT = P + 4 * SD;                                  // [256][3072]
    unsigned short* c_va = (unsigned short*)(P + 5 * SD);         // [3072][256] bf16
    unsigned short* c_av = (unsigned short*)(P + 5 * SD + SD / 2);
    unsigned short* Wqkv = (unsigned short*)(P + 6 * SD);
    unsigned short* Wqka = Wqkv + 131072;
    unsigned short* Wcva = Wqka + 131072;
    unsigned short* Wcav = Wcva + 131072;
    float* bqkv = P + 6 * SD + 262144;
    float* bqka = bqkv + 512;
    float* bcva = bqka + 512;
    float* bcav = bcva + 256;

    auto gmf = [&](const float* A, const unsigned short* W, const float* bias,
                   float* C, int M, int N, int K, int act) {
        dim3 g(N / 64, M / 64);
        if (act) gemm_mfma<1><<<g, 256, 0, stream>>>(A, W, bias, C, M, N, K);
        else     gemm_mfma<0><<<g, 256, 0, stream>>>(A, W, bias, C, M, N, K);
    };
    auto gbt = [&](const float* A, const float* W, const float* bias, float* C,
                   int M, int N, int K, int act) {
        dim3 g((N + 63) / 64, (M + 63) / 64);
        if (act) gemm_bt<1><<<g, 256, 0, stream>>>(A, W, bias, C, M, N, K);
        else     gemm_bt<0><<<g, 256, 0, stream>>>(A, W, bias, C, M, N, K);
    };

    // ---- weight packing (once per launch)
    conv_w<<<2048, 256, 0, stream>>>(vis_W, visbf, 4194304);
    conv_w<<<512,  256, 0, stream>>>(aud_W, audbf, 1048576);
    conv_w<<<384,  256, 0, stream>>>(msv_W, msvbf, 786432);
    conv_w<<<384,  256, 0, stream>>>(msa_W, msabf, 786432);
    conv_w<<<32, 256, 0, stream>>>(mmfa_W + 0 * 65536, Wqkv, 65536);
    conv_w<<<32, 256, 0, stream>>>(mmfa_W + 2 * 65536, Wqkv + 65536, 65536);
    conv_w<<<32, 256, 0, stream>>>(mmfa_W + 1 * 65536, Wqka, 65536);
    conv_w<<<32, 256, 0, stream>>>(mmfa_W + 3 * 65536, Wqka + 65536, 65536);
    pack_kcat<<<256, 256, 0, stream>>>(mmfa_W, Wcva, Wcav);
    pack_bias<<<2, 256, 0, stream>>>(mmfa_b, bqkv, bqka, bcva, bcav);

    // ---- encoders + multiscale
    gmf(img,   visbf, vis_b, vis, 1024, 1024, 4096, 1);
    gmf(audio, audbf, aud_b, aud, 1024, 1024, 1024, 1);
    gmf(vis, msvbf, msv_b, v_ms, 1024, 768, 1024, 1);
    gmf(aud, msabf, msa_b, a_ms, 1024, 768, 1024, 1);

    const int EW_N = (int)SD;
    const int EW_G = (EW_N + 255) / 256;

    auto mmfa = [&](const float* xv, const float* xa, float* outv, float* outa) {
        gmf(xv, Wqkv, bqkv, qkv, 3072, 512, 256, 0);
        gmf(xa, Wqka, bqka, qka, 3072, 512, 256, 0);
        attn_packed<<<1024, 256, 0, stream>>>(qkv, qka, xv, xa, al_v, al_a);
        gemm_sigm<<<dim3(4, 48), 256, 0, stream>>>(al_v, Wcva, bcva, al_v, c_va,
                                                   3072, 256, 512);
        gemm_sigm<<<dim3(4, 48), 256, 0, stream>>>(al_a, Wcav, bcav, al_a, c_av,
                                                   3072, 256, 512);
        bilinear_col<<<dim3(256, 2), 512, 0, stream>>>(c_av, c_va, bil_W, logitsT);
        ew_mix<<<EW_G, 256, 0, stream>>>(logitsT, xv, xa, v_ms, a_ms, t_c,
                                         outv, outa, EW_N);
    };

    mmfa(v_ms, a_ms, x_v2, x_a2);   // M1 stage
    mmfa(x_v2, x_a2, ovb, oab);     // M2 stage

    float* fv = out;
    float* fa = out + 1024 * 128;
    float* pv = out + 2 * 1024 * 128;
    float* pa = pv + 1024 * 10;

    conv_w<<<192, 256, 0, stream>>>(out_W1, W1bf, 393216);
    conv_w<<<32,  256, 0, stream>>>(out_W2, W2bf, 65536);
    gmf(ovb, W1bf, out_b1, hv, 1024, 512, 768, 1);
    gmf(hv,  W2bf, out_b2, fv, 1024, 128, 512, 0);
    gmf(oab, W1bf, out_b1, hv, 1024, 512, 768, 1);
    gmf(hv,  W2bf, out_b2, fa, 1024, 128, 512, 0);

    gbt(fv, clsv_W1, nullptr, hc, 1024, 32, 128, 1);
    gbt(hc, clsv_W2, nullptr, pv, 1024, 10, 32, 0);
    gbt(fa, clsa_W1, nullptr, hc, 1024, 32, 128, 1);
    gbt(hc, clsa_W2, nullptr, pa, 1024, 10, 32, 0);

    (void)in_sizes; (void)n_in; (void)out_size; (void)ws_size;
}